// Round 4
// baseline (838.213 us; speedup 1.0000x reference)
//
#include <hip/hip_runtime.h>
#include <math.h>

#define BB 4
#define NN 1024
#define KK 128
#define DD 32
#define LL 3
#define EH 130
#define EHP 132

__device__ __forceinline__ float lrelu(float x) { return fmaxf(x, 0.1f * x); }

// ---------------- embed: feats = lrelu(feat_ @ embed_w + embed_b) ----------------
__global__ void embed_kernel(const float* __restrict__ feat,
                             const float* __restrict__ w,
                             const float* __restrict__ b,
                             float* __restrict__ out) {
    int t = blockIdx.x * blockDim.x + threadIdx.x;
    if (t >= BB * NN * DD) return;
    int n = t >> 5, o = t & 31;
    const float* f = feat + n * DD;
    float a = b[o];
#pragma unroll
    for (int k = 0; k < DD; k++) a = fmaf(f[k], w[k * DD + o], a);
    out[t] = lrelu(a);
}

// ---------------- transpose c1_w [L][32][128] -> c1wT [L][128][32] ----------------
__global__ void tr_kernel(const float* __restrict__ c1w, float* __restrict__ c1wT) {
    int t = blockIdx.x * blockDim.x + threadIdx.x;
    if (t >= LL * 128 * 32) return;
    int l = t / 4096, r = t % 4096, o = r >> 5, q = r & 31;
    c1wT[t] = c1w[l * 4096 + q * 128 + o];
}

// ---------------- per-layer precompute: HI = feats@Wtop + e1_b ; HJ = feats@Wmid ----------------
__global__ void pre_kernel(const float* __restrict__ feats,
                           const float* __restrict__ e1w,   // [65][130] for this layer
                           const float* __restrict__ e1b,   // [130]
                           float* __restrict__ HI, float* __restrict__ HJ) {
    int t = blockIdx.x * blockDim.x + threadIdx.x;
    if (t >= BB * NN * EHP) return;
    int n = t / EHP, o = t % EHP;
    if (o >= EH) { HI[t] = 0.f; HJ[t] = 0.f; return; }
    const float* f = feats + n * DD;
    float a = e1b[o], c = 0.f;
#pragma unroll
    for (int k = 0; k < DD; k++) a = fmaf(f[k], e1w[k * EH + o], a);
#pragma unroll
    for (int k = 0; k < DD; k++) c = fmaf(f[k], e1w[(DD + k) * EH + o], c);
    HI[t] = a;
    HJ[t] = c;
}

// ---------------- KNN: per-node bitonic sort of (dist,idx) keys ----------------
__global__ __launch_bounds__(256) void knn_kernel(const float* __restrict__ coors,
                                                  int* __restrict__ nbr) {
    int node = blockIdx.x;                 // 0..B*N-1
    int b = node >> 10, i = node & (NN - 1);
    __shared__ float cx[NN], cy[NN];
    __shared__ unsigned long long key[NN];
    const float* cb = coors + (size_t)b * NN * 2;
    for (int j = threadIdx.x; j < NN; j += 256) {
        cx[j] = cb[j * 2];
        cy[j] = cb[j * 2 + 1];
    }
    __syncthreads();
    float cix = cx[i], ciy = cy[i];
    for (int j = threadIdx.x; j < NN; j += 256) {
        float dx = cix - cx[j], dy = ciy - cy[j];
        // match numpy per-op rounding exactly (no fma contraction)
        float d = __fadd_rn(__fmul_rn(dx, dx), __fmul_rn(dy, dy));
        key[j] = ((unsigned long long)__float_as_uint(d) << 32) | (unsigned)j;
    }
    __syncthreads();
    for (int size = 2; size <= NN; size <<= 1) {
        for (int stride = size >> 1; stride >= 1; stride >>= 1) {
            for (int t = threadIdx.x; t < NN / 2; t += 256) {
                int lo = ((t & ~(stride - 1)) << 1) | (t & (stride - 1));
                int hi = lo | stride;
                unsigned long long a = key[lo], c = key[hi];
                bool asc = (lo & size) == 0;
                if ((a > c) == asc) { key[lo] = c; key[hi] = a; }
            }
            __syncthreads();
        }
    }
    if (threadIdx.x < KK)
        nbr[(size_t)node * KK + threadIdx.x] = (int)(key[threadIdx.x] & 0xffffffffu);
}

// ---------------- fused edge MLP + reductions + node MLP, one block per node ----------------
__global__ __launch_bounds__(128) void layer_kernel(
    const float* __restrict__ feats_in,   // [B*N*32]
    const float* __restrict__ coors_in,   // [B*N*2]
    const int*   __restrict__ nbr,        // [B*N*128]
    const float* __restrict__ HI,         // [B*N*132]
    const float* __restrict__ HJ,         // [B*N*132]
    const float* __restrict__ w65,        // [130] = e1_w row 64
    const float* __restrict__ e2w,        // [130][32]
    const float* __restrict__ e2b,        // [32]
    const float* __restrict__ gw,         // [32]
    const float* __restrict__ gb,         // [1]
    const float* __restrict__ c1wT,       // [128][32]
    const float* __restrict__ c1b,        // [128]
    const float* __restrict__ c2w,        // [128]
    const float* __restrict__ c2b,        // [1]
    const float* __restrict__ n1w,        // [64][64]
    const float* __restrict__ n1b,        // [64]
    const float* __restrict__ n2w,        // [64][32]
    const float* __restrict__ n2b,        // [32]
    const float* __restrict__ scale,      // [1]
    float* __restrict__ feats_out,
    float* __restrict__ coors_out) {
    const int node = blockIdx.x;
    const int b = node >> 10;
    const int t = threadIdx.x;            // edge slot 0..127
    const int lane = t & 63, wid = t >> 6;

    __shared__ __align__(16) float shi[EHP];
    __shared__ __align__(16) float sw65[EHP];
    __shared__ float sfi[DD];
    __shared__ float sni[2 * DD];
    __shared__ float sh[2 * DD];
    __shared__ float redm[2][DD];
    __shared__ float redc[2][2];

    // NOTE: EHP (132) > blockDim (128) — must stride; a single `if (t<EHP)` leaves
    // shi[128..131]/sw65[128..131] uninitialized (round-2 NaN/garbage bug).
    for (int q = t; q < EHP; q += 128) {
        shi[q] = HI[(size_t)node * EHP + q];
        sw65[q] = (q < EH) ? w65[q] : 0.f;
    }
    if (t < DD) sfi[t] = feats_in[node * DD + t];
    __syncthreads();

    const float cix = coors_in[node * 2], ciy = coors_in[node * 2 + 1];
    const int j = nbr[(size_t)node * KK + t];
    const float2 cj = *(const float2*)(coors_in + ((size_t)(b * NN) + j) * 2);
    const float dx = cix - cj.x, dy = ciy - cj.y;
    const float rd = __fadd_rn(__fmul_rn(dx, dx), __fmul_rn(dy, dy));  // bitwise == ref dist

    // ---- edge MLP: m = lrelu(lrelu(h1) @ e2_w + e2_b), h1_o = HI_i[o]+HJ_j[o]+rd*w65[o]
    float m[DD];
#pragma unroll
    for (int q = 0; q < DD; q++) m[q] = e2b[q];

    const float4* hjr = (const float4*)(HJ + ((size_t)(b * NN) + j) * EHP);
    const float4* shi4 = (const float4*)shi;
    const float4* sw4 = (const float4*)sw65;

    for (int og = 0; og < 32; og++) {
        float4 hj = hjr[og];
        float4 hi = shi4[og];
        float4 wv = sw4[og];
        float h0 = lrelu(hi.x + hj.x + rd * wv.x);
        float h1 = lrelu(hi.y + hj.y + rd * wv.y);
        float h2 = lrelu(hi.z + hj.z + rd * wv.z);
        float h3 = lrelu(hi.w + hj.w + rd * wv.w);
        const float* w0 = e2w + (og * 4 + 0) * DD;
        const float* w1 = e2w + (og * 4 + 1) * DD;
        const float* w2 = e2w + (og * 4 + 2) * DD;
        const float* w3 = e2w + (og * 4 + 3) * DD;
#pragma unroll
        for (int q = 0; q < DD; q++)
            m[q] = fmaf(h0, w0[q], fmaf(h1, w1[q], fmaf(h2, w2[q], fmaf(h3, w3[q], m[q]))));
    }
    {   // tail o = 128,129
        const float2 hjt = *(const float2*)(HJ + ((size_t)(b * NN) + j) * EHP + 128);
        float h0 = lrelu(shi[128] + hjt.x + rd * sw65[128]);
        float h1 = lrelu(shi[129] + hjt.y + rd * sw65[129]);
        const float* w0 = e2w + 128 * DD;
        const float* w1 = e2w + 129 * DD;
#pragma unroll
        for (int q = 0; q < DD; q++)
            m[q] = fmaf(h0, w0[q], fmaf(h1, w1[q], m[q]));
    }
#pragma unroll
    for (int q = 0; q < DD; q++) m[q] = lrelu(m[q]);

    // ---- soft edge gate
    float g = gb[0];
#pragma unroll
    for (int q = 0; q < DD; q++) g = fmaf(m[q], gw[q], g);
    g = 1.f / (1.f + expf(-g));
#pragma unroll
    for (int q = 0; q < DD; q++) m[q] *= g;

    // ---- coors weight: cw = lrelu(m@c1+b) @ c2 + b
    float cacc = c2b[0];
    for (int o = 0; o < 128; o++) {
        const float* cr = c1wT + o * DD;
        float a = c1b[o];
#pragma unroll
        for (int q = 0; q < DD; q++) a = fmaf(m[q], cr[q], a);
        cacc = fmaf(lrelu(a), c2w[o], cacc);
    }

    const float nrm = fmaxf(sqrtf(rd), 1e-8f);
    const float s = scale[0] / nrm;
    float vx = cacc * (dx * s), vy = cacc * (dy * s);

    // ---- reductions over the 128 edges: m_i (32) and coor delta (2)
    float myred = 0.f;
#pragma unroll
    for (int q = 0; q < DD; q++) {
        float v = m[q];
#pragma unroll
        for (int off = 32; off >= 1; off >>= 1) v += __shfl_xor(v, off);
        if (lane == q) myred = v;
    }
#pragma unroll
    for (int off = 32; off >= 1; off >>= 1) {
        vx += __shfl_xor(vx, off);
        vy += __shfl_xor(vy, off);
    }
    if (lane < DD) redm[wid][lane] = myred;
    if (lane == 0) { redc[wid][0] = vx; redc[wid][1] = vy; }
    __syncthreads();

    // ---- node MLP: feats_out = lrelu([feats|m_i]@n1+b)@n2 + b + feats
    if (t < DD) {
        sni[t] = sfi[t];
        sni[DD + t] = redm[0][t] + redm[1][t];
    }
    __syncthreads();
    if (t < 2 * DD) {
        float a = n1b[t];
#pragma unroll
        for (int k = 0; k < 2 * DD; k++) a = fmaf(sni[k], n1w[k * 2 * DD + t], a);
        sh[t] = lrelu(a);
    }
    __syncthreads();
    if (t < DD) {
        float a = n2b[t];
#pragma unroll
        for (int o = 0; o < 2 * DD; o++) a = fmaf(sh[o], n2w[o * DD + t], a);
        feats_out[node * DD + t] = a + sfi[t];
    }
    if (t == 0) {
        coors_out[node * 2] = cix + redc[0][0] + redc[1][0];
        coors_out[node * 2 + 1] = ciy + redc[0][1] + redc[1][1];
    }
}

extern "C" void kernel_launch(void* const* d_in, const int* in_sizes, int n_in,
                              void* d_out, int out_size, void* d_ws, size_t ws_size,
                              hipStream_t stream) {
    const float* feat_   = (const float*)d_in[0];
    const float* coor_   = (const float*)d_in[1];
    // d_in[2] = batch (int32, unused: equal-size graphs)
    const float* embed_w = (const float*)d_in[3];
    const float* embed_b = (const float*)d_in[4];
    const float* e1_w    = (const float*)d_in[5];
    const float* e1_b    = (const float*)d_in[6];
    const float* e2_w    = (const float*)d_in[7];
    const float* e2_b    = (const float*)d_in[8];
    const float* gate_w  = (const float*)d_in[9];
    const float* gate_b  = (const float*)d_in[10];
    const float* c1_w    = (const float*)d_in[11];
    const float* c1_b    = (const float*)d_in[12];
    const float* c2_w    = (const float*)d_in[13];
    const float* c2_b    = (const float*)d_in[14];
    const float* n1_w    = (const float*)d_in[15];
    const float* n1_b    = (const float*)d_in[16];
    const float* n2_w    = (const float*)d_in[17];
    const float* n2_b    = (const float*)d_in[18];
    const float* cscale  = (const float*)d_in[19];

    float* ws = (float*)d_ws;
    float* feats_a = ws;               ws += BB * NN * DD;
    float* feats_b = ws;               ws += BB * NN * DD;
    float* coors_a = ws;               ws += BB * NN * 2;
    float* coors_b = ws;               ws += BB * NN * 2;
    float* HI      = ws;               ws += BB * NN * EHP;
    float* HJ      = ws;               ws += BB * NN * EHP;
    float* c1wT    = ws;               ws += LL * 128 * 32;
    int*   nbr     = (int*)ws;

    embed_kernel<<<(BB * NN * DD + 255) / 256, 256, 0, stream>>>(feat_, embed_w, embed_b, feats_a);
    tr_kernel<<<(LL * 128 * 32 + 255) / 256, 256, 0, stream>>>(c1_w, c1wT);

    const float* fin = feats_a;
    const float* cin = coor_;
    float* fouts[LL] = {feats_b, feats_a, (float*)d_out};
    float* couts[LL] = {coors_a, coors_b, coors_a};

    for (int l = 0; l < LL; l++) {
        knn_kernel<<<BB * NN, 256, 0, stream>>>(cin, nbr);
        pre_kernel<<<(BB * NN * EHP + 255) / 256, 256, 0, stream>>>(
            fin, e1_w + (size_t)l * 65 * EH, e1_b + (size_t)l * EH, HI, HJ);
        layer_kernel<<<BB * NN, 128, 0, stream>>>(
            fin, cin, nbr, HI, HJ,
            e1_w + ((size_t)l * 65 + 64) * EH,
            e2_w + (size_t)l * EH * DD,
            e2_b + (size_t)l * DD,
            gate_w + (size_t)l * DD,
            gate_b + l,
            c1wT + (size_t)l * 128 * 32,
            c1_b + (size_t)l * 128,
            c2_w + (size_t)l * 128,
            c2_b + l,
            n1_w + (size_t)l * 64 * 64,
            n1_b + (size_t)l * 64,
            n2_w + (size_t)l * 64 * 32,
            n2_b + (size_t)l * DD,
            cscale + l,
            fouts[l], couts[l]);
        fin = fouts[l];
        cin = couts[l];
    }
}

// Round 5
// 639.186 us; speedup vs baseline: 1.3114x; 1.3114x over previous
//
#include <hip/hip_runtime.h>
#include <math.h>

#define BB 4
#define NN 1024
#define KK 128
#define DD 32
#define LL 3
#define EH 130
#define EHP 132

__device__ __forceinline__ float lrelu(float x) { return fmaxf(x, 0.1f * x); }

// ---------------- embed: feats = lrelu(feat_ @ embed_w + embed_b) ----------------
__global__ void embed_kernel(const float* __restrict__ feat,
                             const float* __restrict__ w,
                             const float* __restrict__ b,
                             float* __restrict__ out) {
    int t = blockIdx.x * blockDim.x + threadIdx.x;
    if (t >= BB * NN * DD) return;
    int n = t >> 5, o = t & 31;
    const float* f = feat + n * DD;
    float a = b[o];
#pragma unroll
    for (int k = 0; k < DD; k++) a = fmaf(f[k], w[k * DD + o], a);
    out[t] = lrelu(a);
}

// ---------------- transpose c1_w [L][32][128] -> c1wT [L][128][32] ----------------
__global__ void tr_kernel(const float* __restrict__ c1w, float* __restrict__ c1wT) {
    int t = blockIdx.x * blockDim.x + threadIdx.x;
    if (t >= LL * 128 * 32) return;
    int l = t / 4096, r = t % 4096, o = r >> 5, q = r & 31;
    c1wT[t] = c1w[l * 4096 + q * 128 + o];
}

// ---------------- per-layer precompute: HI = feats@Wtop + e1_b ; HJ = feats@Wmid ----------------
__global__ void pre_kernel(const float* __restrict__ feats,
                           const float* __restrict__ e1w,   // [65][130] for this layer
                           const float* __restrict__ e1b,   // [130]
                           float* __restrict__ HI, float* __restrict__ HJ) {
    int t = blockIdx.x * blockDim.x + threadIdx.x;
    if (t >= BB * NN * EHP) return;
    int n = t / EHP, o = t % EHP;
    if (o >= EH) { HI[t] = 0.f; HJ[t] = 0.f; return; }
    const float* f = feats + n * DD;
    float a = e1b[o], c = 0.f;
#pragma unroll
    for (int k = 0; k < DD; k++) a = fmaf(f[k], e1w[k * EH + o], a);
#pragma unroll
    for (int k = 0; k < DD; k++) c = fmaf(f[k], e1w[(DD + k) * EH + o], c);
    HI[t] = a;
    HJ[t] = c;
}

// ---------------- KNN via exact radix-select on fp32 distance bits ----------------
// Selects the K smallest (dist, idx-tiebreak) — matches jax.lax.top_k(-dist, K)'s
// set exactly. Output order is arbitrary: downstream only sums over neighbors.
__global__ __launch_bounds__(256) void knn_kernel(const float* __restrict__ coors,
                                                  int* __restrict__ nbr) {
    const int node = blockIdx.x;           // 0..B*N-1
    const int b = node >> 10, i = node & (NN - 1);
    const int t = threadIdx.x;

    __shared__ unsigned dkey[NN];          // fp32 dist bit patterns (>=0 -> uint order ok)
    __shared__ unsigned h1[256];           // histogram / scratch reduce
    __shared__ unsigned eqi[NN];           // tie candidate indices
    __shared__ unsigned bsel[2];           // {selected byte, count-below within filter}
    __shared__ unsigned scnt[2];           // {slots taken for <, eq count}

    const float2* cb = (const float2*)(coors + (size_t)b * NN * 2);
    const float2 ci = cb[i];

#pragma unroll
    for (int c = 0; c < 4; c++) {
        int j = t + c * 256;
        float2 cj = cb[j];
        float dx = ci.x - cj.x, dy = ci.y - cj.y;
        // match numpy per-op rounding exactly (no fma contraction)
        float d = __fadd_rn(__fmul_rn(dx, dx), __fmul_rn(dy, dy));
        dkey[j] = __float_as_uint(d);
    }
    if (t < 2) scnt[t] = 0;
    __syncthreads();

    // ---- 4-pass radix select of rank R=K-1 (0-based) over the 32 dist bits
    unsigned maskSo = 0u, valSo = 0u;
    unsigned R_rem = KK - 1;
    unsigned countLess = 0;
    for (int pass = 0; pass < 4; pass++) {
        const int shift = 24 - 8 * pass;
        h1[t] = 0;
        __syncthreads();
#pragma unroll
        for (int c = 0; c < 4; c++) {
            unsigned k = dkey[t + c * 256];
            if ((k & maskSo) == valSo) atomicAdd(&h1[(k >> shift) & 0xFFu], 1u);
        }
        __syncthreads();
        unsigned mine = h1[t];
        // inclusive scan (Hillis-Steele)
        for (int off = 1; off < 256; off <<= 1) {
            unsigned v = h1[t];
            if (t >= off) v += h1[t - off];
            __syncthreads();
            h1[t] = v;
            __syncthreads();
        }
        if (R_rem < h1[t] && R_rem >= h1[t] - mine) {
            bsel[0] = (unsigned)t;
            bsel[1] = h1[t] - mine;   // filtered keys with byte < t
        }
        __syncthreads();
        valSo |= bsel[0] << shift;
        maskSo |= 0xFFu << shift;
        countLess += bsel[1];
        R_rem -= bsel[1];
        __syncthreads();
    }
    const unsigned dstar = valSo;          // exact K-th smallest distance bits

    // ---- gather: all keys < dstar, then ties (== dstar) by smallest index
#pragma unroll
    for (int c = 0; c < 4; c++) {
        int j = t + c * 256;
        unsigned k = dkey[j];
        if (k < dstar) {
            unsigned slot = atomicAdd(&scnt[0], 1u);
            nbr[(size_t)node * KK + slot] = j;
        } else if (k == dstar) {
            unsigned slot = atomicAdd(&scnt[1], 1u);
            eqi[slot] = (unsigned)j;
        }
    }
    __syncthreads();
    const unsigned base = scnt[0];         // == countLess
    const int E = (int)scnt[1];
    const int need = KK - (int)base;       // >= 1
    if (E == need) {                       // common case (usually E == need == 1)
        for (int c = t; c < E; c += 256)
            nbr[(size_t)node * KK + base + c] = (int)eqi[c];
    } else {                               // rare: pick `need` smallest indices
        for (int r = 0; r < need; r++) {
            unsigned best = 0xFFFFFFFFu;
            for (int c = t; c < E; c += 256) best = min(best, eqi[c]);
            h1[t] = best;
            __syncthreads();
            for (int off = 128; off >= 1; off >>= 1) {
                if (t < off) h1[t] = min(h1[t], h1[t + off]);
                __syncthreads();
            }
            unsigned win = h1[0];
            __syncthreads();
            if (t == 0) nbr[(size_t)node * KK + base + r] = (int)win;
            for (int c = t; c < E; c += 256)
                if (eqi[c] == win) eqi[c] = 0xFFFFFFFFu;
            __syncthreads();
        }
    }
}

// ---------------- fused edge MLP + reductions + node MLP, one block per node ----------------
__global__ __launch_bounds__(128) void layer_kernel(
    const float* __restrict__ feats_in,   // [B*N*32]
    const float* __restrict__ coors_in,   // [B*N*2]
    const int*   __restrict__ nbr,        // [B*N*128]
    const float* __restrict__ HI,         // [B*N*132]
    const float* __restrict__ HJ,         // [B*N*132]
    const float* __restrict__ w65,        // [130] = e1_w row 64
    const float* __restrict__ e2w,        // [130][32]
    const float* __restrict__ e2b,        // [32]
    const float* __restrict__ gw,         // [32]
    const float* __restrict__ gb,         // [1]
    const float* __restrict__ c1wT,       // [128][32]
    const float* __restrict__ c1b,        // [128]
    const float* __restrict__ c2w,        // [128]
    const float* __restrict__ c2b,        // [1]
    const float* __restrict__ n1w,        // [64][64]
    const float* __restrict__ n1b,        // [64]
    const float* __restrict__ n2w,        // [64][32]
    const float* __restrict__ n2b,        // [32]
    const float* __restrict__ scale,      // [1]
    float* __restrict__ feats_out,
    float* __restrict__ coors_out) {
    const int node = blockIdx.x;
    const int b = node >> 10;
    const int t = threadIdx.x;            // edge slot 0..127
    const int lane = t & 63, wid = t >> 6;

    __shared__ __align__(16) float shi[EHP];
    __shared__ __align__(16) float sw65[EHP];
    __shared__ float sfi[DD];
    __shared__ float sni[2 * DD];
    __shared__ float sh[2 * DD];
    __shared__ float redm[2][DD];
    __shared__ float redc[2][2];

    // EHP (132) > blockDim (128) — must stride (round-2 uninit-LDS bug).
    for (int q = t; q < EHP; q += 128) {
        shi[q] = HI[(size_t)node * EHP + q];
        sw65[q] = (q < EH) ? w65[q] : 0.f;
    }
    if (t < DD) sfi[t] = feats_in[node * DD + t];
    __syncthreads();

    const float cix = coors_in[node * 2], ciy = coors_in[node * 2 + 1];
    const int j = nbr[(size_t)node * KK + t];
    const float2 cj = *(const float2*)(coors_in + ((size_t)(b * NN) + j) * 2);
    const float dx = cix - cj.x, dy = ciy - cj.y;
    const float rd = __fadd_rn(__fmul_rn(dx, dx), __fmul_rn(dy, dy));  // bitwise == ref dist

    // ---- edge MLP: m = lrelu(lrelu(h1) @ e2_w + e2_b), h1_o = HI_i[o]+HJ_j[o]+rd*w65[o]
    float m[DD];
#pragma unroll
    for (int q = 0; q < DD; q++) m[q] = e2b[q];

    const float4* hjr = (const float4*)(HJ + ((size_t)(b * NN) + j) * EHP);
    const float4* shi4 = (const float4*)shi;
    const float4* sw4 = (const float4*)sw65;

    float4 hj = hjr[0];
#pragma unroll 4
    for (int og = 0; og < 32; og++) {
        float4 hjn = hjr[og + 1];         // og=31 -> hjr[32] = floats 128..131 (in-bounds)
        float4 hi = shi4[og];
        float4 wv = sw4[og];
        float h0 = lrelu(hi.x + hj.x + rd * wv.x);
        float h1 = lrelu(hi.y + hj.y + rd * wv.y);
        float h2 = lrelu(hi.z + hj.z + rd * wv.z);
        float h3 = lrelu(hi.w + hj.w + rd * wv.w);
        const float* w0 = e2w + (og * 4 + 0) * DD;
        const float* w1 = e2w + (og * 4 + 1) * DD;
        const float* w2 = e2w + (og * 4 + 2) * DD;
        const float* w3 = e2w + (og * 4 + 3) * DD;
#pragma unroll
        for (int q = 0; q < DD; q++)
            m[q] = fmaf(h0, w0[q], fmaf(h1, w1[q], fmaf(h2, w2[q], fmaf(h3, w3[q], m[q]))));
        hj = hjn;
    }
    {   // tail o = 128,129 — hj already holds floats 128..131
        float h0 = lrelu(shi[128] + hj.x + rd * sw65[128]);
        float h1 = lrelu(shi[129] + hj.y + rd * sw65[129]);
        const float* w0 = e2w + 128 * DD;
        const float* w1 = e2w + 129 * DD;
#pragma unroll
        for (int q = 0; q < DD; q++)
            m[q] = fmaf(h0, w0[q], fmaf(h1, w1[q], m[q]));
    }
#pragma unroll
    for (int q = 0; q < DD; q++) m[q] = lrelu(m[q]);

    // ---- soft edge gate
    float g = gb[0];
#pragma unroll
    for (int q = 0; q < DD; q++) g = fmaf(m[q], gw[q], g);
    g = 1.f / (1.f + __expf(-g));
#pragma unroll
    for (int q = 0; q < DD; q++) m[q] *= g;

    // ---- coors weight: cw = lrelu(m@c1+b) @ c2 + b
    float cacc = c2b[0];
#pragma unroll 2
    for (int o = 0; o < 128; o++) {
        const float* cr = c1wT + o * DD;
        float a = c1b[o];
#pragma unroll
        for (int q = 0; q < DD; q++) a = fmaf(m[q], cr[q], a);
        cacc = fmaf(lrelu(a), c2w[o], cacc);
    }

    const float nrm = fmaxf(sqrtf(rd), 1e-8f);
    const float s = scale[0] / nrm;
    float vx = cacc * (dx * s), vy = cacc * (dy * s);

    // ---- reductions over the 128 edges: m_i (32) and coor delta (2)
    float myred = 0.f;
#pragma unroll
    for (int q = 0; q < DD; q++) {
        float v = m[q];
#pragma unroll
        for (int off = 32; off >= 1; off >>= 1) v += __shfl_xor(v, off);
        if (lane == q) myred = v;
    }
#pragma unroll
    for (int off = 32; off >= 1; off >>= 1) {
        vx += __shfl_xor(vx, off);
        vy += __shfl_xor(vy, off);
    }
    if (lane < DD) redm[wid][lane] = myred;
    if (lane == 0) { redc[wid][0] = vx; redc[wid][1] = vy; }
    __syncthreads();

    // ---- node MLP: feats_out = lrelu([feats|m_i]@n1+b)@n2 + b + feats
    if (t < DD) {
        sni[t] = sfi[t];
        sni[DD + t] = redm[0][t] + redm[1][t];
    }
    __syncthreads();
    if (t < 2 * DD) {
        float a = n1b[t];
#pragma unroll
        for (int k = 0; k < 2 * DD; k++) a = fmaf(sni[k], n1w[k * 2 * DD + t], a);
        sh[t] = lrelu(a);
    }
    __syncthreads();
    if (t < DD) {
        float a = n2b[t];
#pragma unroll
        for (int o = 0; o < 2 * DD; o++) a = fmaf(sh[o], n2w[o * DD + t], a);
        feats_out[node * DD + t] = a + sfi[t];
    }
    if (t == 0) {
        coors_out[node * 2] = cix + redc[0][0] + redc[1][0];
        coors_out[node * 2 + 1] = ciy + redc[0][1] + redc[1][1];
    }
}

extern "C" void kernel_launch(void* const* d_in, const int* in_sizes, int n_in,
                              void* d_out, int out_size, void* d_ws, size_t ws_size,
                              hipStream_t stream) {
    const float* feat_   = (const float*)d_in[0];
    const float* coor_   = (const float*)d_in[1];
    // d_in[2] = batch (int32, unused: equal-size graphs)
    const float* embed_w = (const float*)d_in[3];
    const float* embed_b = (const float*)d_in[4];
    const float* e1_w    = (const float*)d_in[5];
    const float* e1_b    = (const float*)d_in[6];
    const float* e2_w    = (const float*)d_in[7];
    const float* e2_b    = (const float*)d_in[8];
    const float* gate_w  = (const float*)d_in[9];
    const float* gate_b  = (const float*)d_in[10];
    const float* c1_w    = (const float*)d_in[11];
    const float* c1_b    = (const float*)d_in[12];
    const float* c2_w    = (const float*)d_in[13];
    const float* c2_b    = (const float*)d_in[14];
    const float* n1_w    = (const float*)d_in[15];
    const float* n1_b    = (const float*)d_in[16];
    const float* n2_w    = (const float*)d_in[17];
    const float* n2_b    = (const float*)d_in[18];
    const float* cscale  = (const float*)d_in[19];

    float* ws = (float*)d_ws;
    float* feats_a = ws;               ws += BB * NN * DD;
    float* feats_b = ws;               ws += BB * NN * DD;
    float* coors_a = ws;               ws += BB * NN * 2;
    float* coors_b = ws;               ws += BB * NN * 2;
    float* HI      = ws;               ws += BB * NN * EHP;
    float* HJ      = ws;               ws += BB * NN * EHP;
    float* c1wT    = ws;               ws += LL * 128 * 32;
    int*   nbr     = (int*)ws;

    embed_kernel<<<(BB * NN * DD + 255) / 256, 256, 0, stream>>>(feat_, embed_w, embed_b, feats_a);
    tr_kernel<<<(LL * 128 * 32 + 255) / 256, 256, 0, stream>>>(c1_w, c1wT);

    const float* fin = feats_a;
    const float* cin = coor_;
    float* fouts[LL] = {feats_b, feats_a, (float*)d_out};
    float* couts[LL] = {coors_a, coors_b, coors_a};

    for (int l = 0; l < LL; l++) {
        knn_kernel<<<BB * NN, 256, 0, stream>>>(cin, nbr);
        pre_kernel<<<(BB * NN * EHP + 255) / 256, 256, 0, stream>>>(
            fin, e1_w + (size_t)l * 65 * EH, e1_b + (size_t)l * EH, HI, HJ);
        layer_kernel<<<BB * NN, 128, 0, stream>>>(
            fin, cin, nbr, HI, HJ,
            e1_w + ((size_t)l * 65 + 64) * EH,
            e2_w + (size_t)l * EH * DD,
            e2_b + (size_t)l * DD,
            gate_w + (size_t)l * DD,
            gate_b + l,
            c1wT + (size_t)l * 128 * 32,
            c1_b + (size_t)l * 128,
            c2_w + (size_t)l * 128,
            c2_b + l,
            n1_w + (size_t)l * 64 * 64,
            n1_b + (size_t)l * 64,
            n2_w + (size_t)l * 64 * 32,
            n2_b + (size_t)l * DD,
            cscale + l,
            fouts[l], couts[l]);
        fin = fouts[l];
        cin = couts[l];
    }
}

// Round 6
// 402.501 us; speedup vs baseline: 2.0825x; 1.5880x over previous
//
#include <hip/hip_runtime.h>
#include <math.h>

#define BB 4
#define NN 1024
#define KK 128
#define DD 32
#define LL 3
#define EH 130
#define EHP 132

typedef float f32x4 __attribute__((ext_vector_type(4)));
typedef short s16x8 __attribute__((ext_vector_type(8)));

__device__ __forceinline__ float lrelu(float x) { return fmaxf(x, 0.1f * x); }

// two fp32 -> packed bf16 pair (round-half-up: 1 add per value, negligible bias)
__device__ __forceinline__ unsigned pk2_bf16(float a, float b) {
    unsigned ua = __float_as_uint(a) + 0x8000u;
    unsigned ub = __float_as_uint(b) + 0x8000u;
    return (ua >> 16) | (ub & 0xffff0000u);
}
__device__ __forceinline__ unsigned short bf16_hu(float v) {
    return (unsigned short)((__float_as_uint(v) + 0x8000u) >> 16);
}
__device__ __forceinline__ unsigned short bf16_rne(float v) {
    unsigned u = __float_as_uint(v);
    return (unsigned short)((u + 0x7fffu + ((u >> 16) & 1u)) >> 16);
}

// ---------------- embed: feats = lrelu(feat_ @ embed_w + embed_b) ----------------
__global__ void embed_kernel(const float* __restrict__ feat,
                             const float* __restrict__ w,
                             const float* __restrict__ b,
                             float* __restrict__ out) {
    int t = blockIdx.x * blockDim.x + threadIdx.x;
    if (t >= BB * NN * DD) return;
    int n = t >> 5, o = t & 31;
    const float* f = feat + n * DD;
    float a = b[o];
#pragma unroll
    for (int k = 0; k < DD; k++) a = fmaf(f[k], w[k * DD + o], a);
    out[t] = lrelu(a);
}

// ---------------- B-fragment precompute (bf16, fragment-ordered) ----------------
// e2f: [L][4 chunks][2 ntiles][64 lanes][8]  (k = 32c + (lane>>4)*8 + j, n = nt*16 + (lane&15))
// c1f: [L][8 ntiles][64 lanes][8]            (k = (lane>>4)*8 + j,      n = nt*16 + (lane&15))
__global__ void frag_kernel(const float* __restrict__ e2w, const float* __restrict__ c1w,
                            unsigned short* __restrict__ e2f, unsigned short* __restrict__ c1f) {
    int t = blockIdx.x * 256 + threadIdx.x;
    if (t < LL * 4 * 2 * 512) {
        int jj = t & 7, lane = (t >> 3) & 63, nt = (t >> 9) & 1, c = (t >> 10) & 3, l = t >> 12;
        int k = 32 * c + (lane >> 4) * 8 + jj;           // 0..127 < 130
        int n = nt * 16 + (lane & 15);
        e2f[t] = bf16_rne(e2w[(size_t)l * EH * DD + k * DD + n]);
    } else {
        int u = t - LL * 4 * 2 * 512;
        if (u < LL * 8 * 512) {
            int jj = u & 7, lane = (u >> 3) & 63, nt = (u >> 9) & 7, l = u >> 12;
            int k = (lane >> 4) * 8 + jj;                // 0..31
            int n = nt * 16 + (lane & 15);
            c1f[u] = bf16_rne(c1w[(size_t)l * DD * 128 + k * 128 + n]);
        }
    }
}

// ---------------- per-layer precompute: HI = feats@Wtop + e1_b ; HJ = feats@Wmid ----------------
__global__ void pre_kernel(const float* __restrict__ feats,
                           const float* __restrict__ e1w,   // [65][130] for this layer
                           const float* __restrict__ e1b,   // [130]
                           float* __restrict__ HI, float* __restrict__ HJ) {
    int t = blockIdx.x * blockDim.x + threadIdx.x;
    if (t >= BB * NN * EHP) return;
    int n = t / EHP, o = t % EHP;
    if (o >= EH) { HI[t] = 0.f; HJ[t] = 0.f; return; }
    const float* f = feats + n * DD;
    float a = e1b[o], c = 0.f;
#pragma unroll
    for (int k = 0; k < DD; k++) a = fmaf(f[k], e1w[k * EH + o], a);
#pragma unroll
    for (int k = 0; k < DD; k++) c = fmaf(f[k], e1w[(DD + k) * EH + o], c);
    HI[t] = a;
    HJ[t] = c;
}

// ---------------- KNN via exact radix-select on fp32 distance bits ----------------
__global__ __launch_bounds__(256) void knn_kernel(const float* __restrict__ coors,
                                                  int* __restrict__ nbr) {
    const int node = blockIdx.x;
    const int b = node >> 10, i = node & (NN - 1);
    const int t = threadIdx.x;

    __shared__ unsigned dkey[NN];
    __shared__ unsigned h1[256];
    __shared__ unsigned eqi[NN];
    __shared__ unsigned bsel[2];
    __shared__ unsigned scnt[2];

    const float2* cb = (const float2*)(coors + (size_t)b * NN * 2);
    const float2 ci = cb[i];

#pragma unroll
    for (int c = 0; c < 4; c++) {
        int j = t + c * 256;
        float2 cj = cb[j];
        float dx = ci.x - cj.x, dy = ci.y - cj.y;
        float d = __fadd_rn(__fmul_rn(dx, dx), __fmul_rn(dy, dy));
        dkey[j] = __float_as_uint(d);
    }
    if (t < 2) scnt[t] = 0;
    __syncthreads();

    unsigned maskSo = 0u, valSo = 0u;
    unsigned R_rem = KK - 1;
    for (int pass = 0; pass < 4; pass++) {
        const int shift = 24 - 8 * pass;
        h1[t] = 0;
        __syncthreads();
#pragma unroll
        for (int c = 0; c < 4; c++) {
            unsigned k = dkey[t + c * 256];
            if ((k & maskSo) == valSo) atomicAdd(&h1[(k >> shift) & 0xFFu], 1u);
        }
        __syncthreads();
        unsigned mine = h1[t];
        for (int off = 1; off < 256; off <<= 1) {
            unsigned v = h1[t];
            if (t >= off) v += h1[t - off];
            __syncthreads();
            h1[t] = v;
            __syncthreads();
        }
        if (R_rem < h1[t] && R_rem >= h1[t] - mine) {
            bsel[0] = (unsigned)t;
            bsel[1] = h1[t] - mine;
        }
        __syncthreads();
        valSo |= bsel[0] << shift;
        maskSo |= 0xFFu << shift;
        R_rem -= bsel[1];
        __syncthreads();
    }
    const unsigned dstar = valSo;

#pragma unroll
    for (int c = 0; c < 4; c++) {
        int j = t + c * 256;
        unsigned k = dkey[j];
        if (k < dstar) {
            unsigned slot = atomicAdd(&scnt[0], 1u);
            nbr[(size_t)node * KK + slot] = j;
        } else if (k == dstar) {
            unsigned slot = atomicAdd(&scnt[1], 1u);
            eqi[slot] = (unsigned)j;
        }
    }
    __syncthreads();
    const unsigned base = scnt[0];
    const int E = (int)scnt[1];
    const int need = KK - (int)base;
    if (E == need) {
        for (int c = t; c < E; c += 256)
            nbr[(size_t)node * KK + base + c] = (int)eqi[c];
    } else {
        for (int r = 0; r < need; r++) {
            unsigned best = 0xFFFFFFFFu;
            for (int c = t; c < E; c += 256) best = min(best, eqi[c]);
            h1[t] = best;
            __syncthreads();
            for (int off = 128; off >= 1; off >>= 1) {
                if (t < off) h1[t] = min(h1[t], h1[t + off]);
                __syncthreads();
            }
            unsigned win = h1[0];
            __syncthreads();
            if (t == 0) nbr[(size_t)node * KK + base + r] = (int)win;
            for (int c = t; c < E; c += 256)
                if (eqi[c] == win) eqi[c] = 0xFFFFFFFFu;
            __syncthreads();
        }
    }
}

// ---------------- fused layer: MFMA e2 + gate + MFMA c1 + reductions + node MLP ----------------
// Block = 1 node, 128 threads = 2 waves. Wave w owns edge rows 64w..64w+63, so the
// h1-produce -> MFMA-consume LDS pipeline is wave-private (no barriers in the K loop).
// MFMA layouts (gfx950, verified in guide): A[m=lane&15][k=(lane>>4)*8+j],
// B[k=(lane>>4)*8+j][n=lane&15], C/D[row=(lane>>4)*4+r][col=lane&15].
__global__ __launch_bounds__(128) void layer_kernel(
    const float* __restrict__ feats_in, const float* __restrict__ coors_in,
    const int*   __restrict__ nbr,
    const float* __restrict__ HI, const float* __restrict__ HJ,
    const float* __restrict__ w65,        // e1_w row 64 [130]
    const float* __restrict__ e2w,        // [130][32] (for k=128,129 tail)
    const float* __restrict__ e2b,        // [32]
    const unsigned short* __restrict__ e2f,  // this layer's e2 B-frags
    const unsigned short* __restrict__ c1f,  // this layer's c1 B-frags
    const float* __restrict__ gw, const float* __restrict__ gb,
    const float* __restrict__ c1b, const float* __restrict__ c2w, const float* __restrict__ c2b,
    const float* __restrict__ n1w, const float* __restrict__ n1b,
    const float* __restrict__ n2w, const float* __restrict__ n2b,
    const float* __restrict__ scale,
    float* __restrict__ feats_out, float* __restrict__ coors_out) {
    const int node = blockIdx.x;
    const int b = node >> 10;
    const int t = threadIdx.x;            // edge row 0..127
    const int lane = t & 63, wid = t >> 6;
    const int ln = lane & 15, q = lane >> 4;
    const int rowbase = wid * 64;

    __shared__ __align__(16) float shi[EHP];
    __shared__ __align__(16) float sw65[EHP];
    __shared__ __align__(16) unsigned short sA[128 * 32];   // bf16 A tile (h1 chunks, then m)
    __shared__ float sx0[128], sx1[128], su[128], sv[128];
    __shared__ float sgw[DD], se2b[DD], sfi[DD];
    __shared__ float sc1b[128], sc2w[128];
    __shared__ float redm[2][DD], redc[2][2];
    __shared__ float sni[2 * DD], shd[2 * DD];

    for (int u = t; u < EHP; u += 128) {   // strided: EHP > blockDim
        shi[u] = HI[(size_t)node * EHP + u];
        sw65[u] = (u < EH) ? w65[u] : 0.f;
    }
    if (t < DD) { sfi[t] = feats_in[node * DD + t]; sgw[t] = gw[t]; se2b[t] = e2b[t]; }
    sc1b[t] = c1b[t];
    sc2w[t] = c2w[t];
    __syncthreads();

    // ---- per-edge setup (exact fp32, matches reference distance bitwise)
    const float cix = coors_in[node * 2], ciy = coors_in[node * 2 + 1];
    const int j = nbr[(size_t)node * KK + t];
    const float2 cj = *(const float2*)(coors_in + ((size_t)(b * NN) + j) * 2);
    const float dx = cix - cj.x, dy = ciy - cj.y;
    const float rd = __fadd_rn(__fmul_rn(dx, dx), __fmul_rn(dy, dy));
    const float nrm = fmaxf(sqrtf(rd), 1e-8f);
    const float s = scale[0] / nrm;
    su[t] = dx * s;
    sv[t] = dy * s;

    const float* hjrow = HJ + ((size_t)(b * NN) + j) * EHP;
    {   // h1 features k=128,129 kept exact fp32 (handled via VALU tail)
        const float2 hjt = *(const float2*)(hjrow + 128);
        sx0[t] = lrelu(shi[128] + hjt.x + rd * sw65[128]);
        sx1[t] = lrelu(shi[129] + hjt.y + rd * sw65[129]);
    }

    const float4* hjr  = (const float4*)hjrow;
    const float4* shi4 = (const float4*)shi;
    const float4* sw4  = (const float4*)sw65;

    const f32x4 zz = {0.f, 0.f, 0.f, 0.f};
    f32x4 accA[4][2];
#pragma unroll
    for (int mt = 0; mt < 4; mt++) { accA[mt][0] = zz; accA[mt][1] = zz; }

    // ---- e2 GEMM over K chunks of 32 (k = 0..127)
#pragma unroll 1
    for (int c = 0; c < 4; c++) {
        uint2* dst = (uint2*)&sA[t * 32];
#pragma unroll
        for (int u = 0; u < 8; u++) {
            float4 hj = hjr[c * 8 + u];
            float4 hi = shi4[c * 8 + u];
            float4 wv = sw4[c * 8 + u];
            float h0 = lrelu(hi.x + hj.x + rd * wv.x);
            float h1 = lrelu(hi.y + hj.y + rd * wv.y);
            float h2 = lrelu(hi.z + hj.z + rd * wv.z);
            float h3 = lrelu(hi.w + hj.w + rd * wv.w);
            dst[u] = make_uint2(pk2_bf16(h0, h1), pk2_bf16(h2, h3));
        }
        s16x8 b0 = *(const s16x8*)(e2f + ((c * 2 + 0) * 64 + lane) * 8);
        s16x8 b1 = *(const s16x8*)(e2f + ((c * 2 + 1) * 64 + lane) * 8);
#pragma unroll
        for (int mt = 0; mt < 4; mt++) {
            const s16x8 a = *(const s16x8*)&sA[(rowbase + mt * 16 + ln) * 32 + q * 8];
            accA[mt][0] = __builtin_amdgcn_mfma_f32_16x16x32_bf16(a, b0, accA[mt][0], 0, 0, 0);
            accA[mt][1] = __builtin_amdgcn_mfma_f32_16x16x32_bf16(a, b1, accA[mt][1], 0, 0, 0);
        }
    }

    // ---- e2 epilogue: bias + exact k=128,129 tail + lrelu (C layout)
#pragma unroll
    for (int nt = 0; nt < 2; nt++) {
        const int col = nt * 16 + ln;
        const float w128 = e2w[128 * DD + col];
        const float w129 = e2w[129 * DD + col];
        const float bv = se2b[col];
#pragma unroll
        for (int mt = 0; mt < 4; mt++)
#pragma unroll
            for (int r = 0; r < 4; r++) {
                const int row = rowbase + mt * 16 + q * 4 + r;
                accA[mt][nt][r] = lrelu(accA[mt][nt][r] + bv + sx0[row] * w128 + sx1[row] * w129);
            }
    }

    // ---- soft edge gate (per row; reduce over the 16 col-lanes)
    const float gbv = gb[0];
#pragma unroll
    for (int mt = 0; mt < 4; mt++) {
        float p[4];
#pragma unroll
        for (int r = 0; r < 4; r++)
            p[r] = accA[mt][0][r] * sgw[ln] + accA[mt][1][r] * sgw[16 + ln];
#pragma unroll
        for (int off = 1; off <= 8; off <<= 1)
#pragma unroll
            for (int r = 0; r < 4; r++) p[r] += __shfl_xor(p[r], off);
#pragma unroll
        for (int r = 0; r < 4; r++) {
            const float g = 1.f / (1.f + __expf(-(p[r] + gbv)));
            accA[mt][0][r] *= g;
            accA[mt][1][r] *= g;
        }
    }

    // ---- m_i partials (sum over this wave's 64 rows), fp32 exact m
    float mi0 = 0.f, mi1 = 0.f;
#pragma unroll
    for (int mt = 0; mt < 4; mt++)
#pragma unroll
        for (int r = 0; r < 4; r++) { mi0 += accA[mt][0][r]; mi1 += accA[mt][1][r]; }
    mi0 += __shfl_xor(mi0, 16); mi0 += __shfl_xor(mi0, 32);
    mi1 += __shfl_xor(mi1, 16); mi1 += __shfl_xor(mi1, 32);
    if (lane < 16) { redm[wid][lane] = mi0; redm[wid][16 + lane] = mi1; }

    // ---- write m as bf16 A-tile (wave-private rows), then c1 GEMM
#pragma unroll
    for (int mt = 0; mt < 4; mt++)
#pragma unroll
        for (int nt = 0; nt < 2; nt++) {
            const int col = nt * 16 + ln;
#pragma unroll
            for (int r = 0; r < 4; r++)
                sA[(rowbase + mt * 16 + q * 4 + r) * 32 + col] = bf16_hu(accA[mt][nt][r]);
        }

    s16x8 a4[4];
#pragma unroll
    for (int mt = 0; mt < 4; mt++)
        a4[mt] = *(const s16x8*)&sA[(rowbase + mt * 16 + ln) * 32 + q * 8];

    float cacc[4][4];
#pragma unroll
    for (int mt = 0; mt < 4; mt++)
#pragma unroll
        for (int r = 0; r < 4; r++) cacc[mt][r] = 0.f;

#pragma unroll 1
    for (int g = 0; g < 4; g++) {
        s16x8 bc0 = *(const s16x8*)(c1f + ((2 * g + 0) * 64 + lane) * 8);
        s16x8 bc1 = *(const s16x8*)(c1f + ((2 * g + 1) * 64 + lane) * 8);
        f32x4 c20[4], c21[4];
#pragma unroll
        for (int mt = 0; mt < 4; mt++) {
            c20[mt] = __builtin_amdgcn_mfma_f32_16x16x32_bf16(a4[mt], bc0, zz, 0, 0, 0);
            c21[mt] = __builtin_amdgcn_mfma_f32_16x16x32_bf16(a4[mt], bc1, zz, 0, 0, 0);
        }
#pragma unroll
        for (int h = 0; h < 2; h++) {
            const int col = (2 * g + h) * 16 + ln;
            const float c1bv = sc1b[col], c2wv = sc2w[col];
#pragma unroll
            for (int mt = 0; mt < 4; mt++)
#pragma unroll
                for (int r = 0; r < 4; r++) {
                    const float v = (h ? c21[mt][r] : c20[mt][r]) + c1bv;
                    cacc[mt][r] = fmaf(lrelu(v), c2wv, cacc[mt][r]);
                }
        }
    }
#pragma unroll
    for (int off = 1; off <= 8; off <<= 1)
#pragma unroll
        for (int mt = 0; mt < 4; mt++)
#pragma unroll
            for (int r = 0; r < 4; r++) cacc[mt][r] += __shfl_xor(cacc[mt][r], off);

    const float c2bv = c2b[0];
    float vxp = 0.f, vyp = 0.f;
    if (ln == 0) {   // one lane per quad owns its 4 rows
#pragma unroll
        for (int mt = 0; mt < 4; mt++)
#pragma unroll
            for (int r = 0; r < 4; r++) {
                const int row = rowbase + mt * 16 + q * 4 + r;
                const float cw = cacc[mt][r] + c2bv;
                vxp = fmaf(cw, su[row], vxp);
                vyp = fmaf(cw, sv[row], vyp);
            }
    }
    vxp += __shfl_xor(vxp, 16); vxp += __shfl_xor(vxp, 32);
    vyp += __shfl_xor(vyp, 16); vyp += __shfl_xor(vyp, 32);
    if (lane == 0) { redc[wid][0] = vxp; redc[wid][1] = vyp; }

    // ---- cross-wave combine + node MLP + coords
    __syncthreads();
    if (t < DD) {
        sni[t] = sfi[t];
        sni[DD + t] = redm[0][t] + redm[1][t];
    }
    __syncthreads();
    if (t < 2 * DD) {
        float a = n1b[t];
#pragma unroll
        for (int k = 0; k < 2 * DD; k++) a = fmaf(sni[k], n1w[k * 2 * DD + t], a);
        shd[t] = lrelu(a);
    }
    __syncthreads();
    if (t < DD) {
        float a = n2b[t];
#pragma unroll
        for (int o = 0; o < 2 * DD; o++) a = fmaf(shd[o], n2w[o * DD + t], a);
        feats_out[node * DD + t] = a + sfi[t];
    }
    if (t == 0) {
        coors_out[node * 2] = cix + redc[0][0] + redc[1][0];
        coors_out[node * 2 + 1] = ciy + redc[0][1] + redc[1][1];
    }
}

extern "C" void kernel_launch(void* const* d_in, const int* in_sizes, int n_in,
                              void* d_out, int out_size, void* d_ws, size_t ws_size,
                              hipStream_t stream) {
    const float* feat_   = (const float*)d_in[0];
    const float* coor_   = (const float*)d_in[1];
    // d_in[2] = batch (int32, unused: equal-size graphs)
    const float* embed_w = (const float*)d_in[3];
    const float* embed_b = (const float*)d_in[4];
    const float* e1_w    = (const float*)d_in[5];
    const float* e1_b    = (const float*)d_in[6];
    const float* e2_w    = (const float*)d_in[7];
    const float* e2_b    = (const float*)d_in[8];
    const float* gate_w  = (const float*)d_in[9];
    const float* gate_b  = (const float*)d_in[10];
    const float* c1_w    = (const float*)d_in[11];
    const float* c1_b    = (const float*)d_in[12];
    const float* c2_w    = (const float*)d_in[13];
    const float* c2_b    = (const float*)d_in[14];
    const float* n1_w    = (const float*)d_in[15];
    const float* n1_b    = (const float*)d_in[16];
    const float* n2_w    = (const float*)d_in[17];
    const float* n2_b    = (const float*)d_in[18];
    const float* cscale  = (const float*)d_in[19];

    float* ws = (float*)d_ws;
    float* feats_a = ws;               ws += BB * NN * DD;
    float* feats_b = ws;               ws += BB * NN * DD;
    float* coors_a = ws;               ws += BB * NN * 2;
    float* coors_b = ws;               ws += BB * NN * 2;
    float* HI      = ws;               ws += BB * NN * EHP;
    float* HJ      = ws;               ws += BB * NN * EHP;
    unsigned short* e2f = (unsigned short*)ws;   // LL*4096 ushorts
    unsigned short* c1f = e2f + LL * 4096;       // LL*4096 ushorts
    ws += (2 * LL * 4096) / 2;
    int* nbr = (int*)ws;

    embed_kernel<<<(BB * NN * DD + 255) / 256, 256, 0, stream>>>(feat_, embed_w, embed_b, feats_a);
    frag_kernel<<<(2 * LL * 4096 + 255) / 256, 256, 0, stream>>>(e2_w, c1_w, e2f, c1f);

    const float* fin = feats_a;
    const float* cin = coor_;
    float* fouts[LL] = {feats_b, feats_a, (float*)d_out};
    float* couts[LL] = {coors_a, coors_b, coors_a};

    for (int l = 0; l < LL; l++) {
        knn_kernel<<<BB * NN, 256, 0, stream>>>(cin, nbr);
        pre_kernel<<<(BB * NN * EHP + 255) / 256, 256, 0, stream>>>(
            fin, e1_w + (size_t)l * 65 * EH, e1_b + (size_t)l * EH, HI, HJ);
        layer_kernel<<<BB * NN, 128, 0, stream>>>(
            fin, cin, nbr, HI, HJ,
            e1_w + ((size_t)l * 65 + 64) * EH,
            e2_w + (size_t)l * EH * DD,
            e2_b + (size_t)l * DD,
            e2f + (size_t)l * 4096,
            c1f + (size_t)l * 4096,
            gate_w + (size_t)l * DD,
            gate_b + l,
            c1_b + (size_t)l * 128,
            c2_w + (size_t)l * 128,
            c2_b + l,
            n1_w + (size_t)l * 64 * 64,
            n1_b + (size_t)l * 64,
            n2_w + (size_t)l * 64 * 32,
            n2_b + (size_t)l * DD,
            cscale + l,
            fouts[l], couts[l]);
        fin = fouts[l];
        cin = couts[l];
    }
}

// Round 7
// 391.388 us; speedup vs baseline: 2.1416x; 1.0284x over previous
//
#include <hip/hip_runtime.h>
#include <hip/hip_bf16.h>
#include <math.h>

#define BB 4
#define NN 1024
#define KK 128
#define DD 32
#define LL 3
#define EH 130
#define EHP 132

typedef float f32x4 __attribute__((ext_vector_type(4)));
typedef short s16x8 __attribute__((ext_vector_type(8)));

__device__ __forceinline__ float lrelu(float x) { return fmaxf(x, 0.1f * x); }

__device__ __forceinline__ unsigned pk2(float a, float b) {   // v_cvt_pk_bf16_f32 (RNE)
    __hip_bfloat162 h = __float22bfloat162_rn(float2{a, b});
    return *(unsigned*)&h;
}
__device__ __forceinline__ unsigned short bf16_hu(float v) {
    return (unsigned short)((__float_as_uint(v) + 0x8000u) >> 16);
}
__device__ __forceinline__ unsigned short bf16_rne(float v) {
    unsigned u = __float_as_uint(v);
    return (unsigned short)((u + 0x7fffu + ((u >> 16) & 1u)) >> 16);
}

// ---------------- embed: feats = lrelu(feat_ @ embed_w + embed_b) ----------------
__global__ void embed_kernel(const float* __restrict__ feat,
                             const float* __restrict__ w,
                             const float* __restrict__ b,
                             float* __restrict__ out) {
    int t = blockIdx.x * blockDim.x + threadIdx.x;
    if (t >= BB * NN * DD) return;
    int n = t >> 5, o = t & 31;
    const float* f = feat + n * DD;
    float a = b[o];
#pragma unroll
    for (int k = 0; k < DD; k++) a = fmaf(f[k], w[k * DD + o], a);
    out[t] = lrelu(a);
}

// ---------------- B-fragment precompute (bf16, fragment-ordered) ----------------
// e2f: [L][4 chunks][2 ntiles][64 lanes][8]  (k = 32c + (lane>>4)*8 + j, n = nt*16 + (lane&15))
// c1f: [L][8 ntiles][64 lanes][8]            (k = (lane>>4)*8 + j,      n = nt*16 + (lane&15))
__global__ void frag_kernel(const float* __restrict__ e2w, const float* __restrict__ c1w,
                            unsigned short* __restrict__ e2f, unsigned short* __restrict__ c1f) {
    int t = blockIdx.x * 256 + threadIdx.x;
    if (t < LL * 4 * 2 * 512) {
        int jj = t & 7, lane = (t >> 3) & 63, nt = (t >> 9) & 1, c = (t >> 10) & 3, l = t >> 12;
        int k = 32 * c + (lane >> 4) * 8 + jj;           // 0..127 < 130
        int n = nt * 16 + (lane & 15);
        e2f[t] = bf16_rne(e2w[(size_t)l * EH * DD + k * DD + n]);
    } else {
        int u = t - LL * 4 * 2 * 512;
        if (u < LL * 8 * 512) {
            int jj = u & 7, lane = (u >> 3) & 63, nt = (u >> 9) & 7, l = u >> 12;
            int k = (lane >> 4) * 8 + jj;                // 0..31
            int n = nt * 16 + (lane & 15);
            c1f[u] = bf16_rne(c1w[(size_t)l * DD * 128 + k * 128 + n]);
        }
    }
}

// ---------------- per-layer precompute: HI = feats@Wtop + e1_b ; HJ = feats@Wmid ----------------
__global__ void pre_kernel(const float* __restrict__ feats,
                           const float* __restrict__ e1w,   // [65][130] for this layer
                           const float* __restrict__ e1b,   // [130]
                           float* __restrict__ HI, float* __restrict__ HJ) {
    int t = blockIdx.x * blockDim.x + threadIdx.x;
    if (t >= BB * NN * EHP) return;
    int n = t / EHP, o = t % EHP;
    if (o >= EH) { HI[t] = 0.f; HJ[t] = 0.f; return; }
    const float* f = feats + n * DD;
    float a = e1b[o], c = 0.f;
#pragma unroll
    for (int k = 0; k < DD; k++) a = fmaf(f[k], e1w[k * EH + o], a);
#pragma unroll
    for (int k = 0; k < DD; k++) c = fmaf(f[k], e1w[(DD + k) * EH + o], c);
    HI[t] = a;
    HJ[t] = c;
}

// ---------------- KNN via exact radix-select on fp32 distance bits ----------------
__global__ __launch_bounds__(256) void knn_kernel(const float* __restrict__ coors,
                                                  int* __restrict__ nbr) {
    const int node = blockIdx.x;
    const int b = node >> 10, i = node & (NN - 1);
    const int t = threadIdx.x;

    __shared__ unsigned dkey[NN];
    __shared__ unsigned h1[256];
    __shared__ unsigned eqi[NN];
    __shared__ unsigned bsel[2];
    __shared__ unsigned scnt[2];

    const float2* cb = (const float2*)(coors + (size_t)b * NN * 2);
    const float2 ci = cb[i];

#pragma unroll
    for (int c = 0; c < 4; c++) {
        int j = t + c * 256;
        float2 cj = cb[j];
        float dx = ci.x - cj.x, dy = ci.y - cj.y;
        float d = __fadd_rn(__fmul_rn(dx, dx), __fmul_rn(dy, dy));
        dkey[j] = __float_as_uint(d);
    }
    if (t < 2) scnt[t] = 0;
    __syncthreads();

    unsigned maskSo = 0u, valSo = 0u;
    unsigned R_rem = KK - 1;
    for (int pass = 0; pass < 4; pass++) {
        const int shift = 24 - 8 * pass;
        h1[t] = 0;
        __syncthreads();
#pragma unroll
        for (int c = 0; c < 4; c++) {
            unsigned k = dkey[t + c * 256];
            if ((k & maskSo) == valSo) atomicAdd(&h1[(k >> shift) & 0xFFu], 1u);
        }
        __syncthreads();
        unsigned mine = h1[t];
        for (int off = 1; off < 256; off <<= 1) {
            unsigned v = h1[t];
            if (t >= off) v += h1[t - off];
            __syncthreads();
            h1[t] = v;
            __syncthreads();
        }
        if (R_rem < h1[t] && R_rem >= h1[t] - mine) {
            bsel[0] = (unsigned)t;
            bsel[1] = h1[t] - mine;
        }
        __syncthreads();
        valSo |= bsel[0] << shift;
        maskSo |= 0xFFu << shift;
        R_rem -= bsel[1];
        __syncthreads();
    }
    const unsigned dstar = valSo;

#pragma unroll
    for (int c = 0; c < 4; c++) {
        int j = t + c * 256;
        unsigned k = dkey[j];
        if (k < dstar) {
            unsigned slot = atomicAdd(&scnt[0], 1u);
            nbr[(size_t)node * KK + slot] = j;
        } else if (k == dstar) {
            unsigned slot = atomicAdd(&scnt[1], 1u);
            eqi[slot] = (unsigned)j;
        }
    }
    __syncthreads();
    const unsigned base = scnt[0];
    const int E = (int)scnt[1];
    const int need = KK - (int)base;
    if (E == need) {
        for (int c = t; c < E; c += 256)
            nbr[(size_t)node * KK + base + c] = (int)eqi[c];
    } else {
        for (int r = 0; r < need; r++) {
            unsigned best = 0xFFFFFFFFu;
            for (int c = t; c < E; c += 256) best = min(best, eqi[c]);
            h1[t] = best;
            __syncthreads();
            for (int off = 128; off >= 1; off >>= 1) {
                if (t < off) h1[t] = min(h1[t], h1[t + off]);
                __syncthreads();
            }
            unsigned win = h1[0];
            __syncthreads();
            if (t == 0) nbr[(size_t)node * KK + base + r] = (int)win;
            for (int c = t; c < E; c += 256)
                if (eqi[c] == win) eqi[c] = 0xFFFFFFFFu;
            __syncthreads();
        }
    }
}

// ---------------- fused layer: MFMA e2 + gate + MFMA c1 + reductions + node MLP ----------------
// Block = 1 node, 128 threads = 2 waves; wave w owns edge rows 64w..64w+63.
// e2 A-fragments are computed DIRECTLY in the consuming lane (rows fetched via __shfl
// of (j, rd)) — no LDS staging. The m-transpose uses a wave-private bf16 tile with
// physical-row swizzle prow=((row&3)<<4)|(row>>2): writes <=2-way, reads wire-limited.
__global__ __launch_bounds__(128) void layer_kernel(
    const float* __restrict__ feats_in, const float* __restrict__ coors_in,
    const int*   __restrict__ nbr,
    const float* __restrict__ HI, const float* __restrict__ HJ,
    const float* __restrict__ w65,        // e1_w row 64 [130]
    const float* __restrict__ e2w,        // [130][32] (for k=128,129 tail)
    const float* __restrict__ e2b,        // [32]
    const unsigned short* __restrict__ e2f,  // this layer's e2 B-frags
    const unsigned short* __restrict__ c1f,  // this layer's c1 B-frags
    const float* __restrict__ gw, const float* __restrict__ gb,
    const float* __restrict__ c1b, const float* __restrict__ c2w, const float* __restrict__ c2b,
    const float* __restrict__ n1w, const float* __restrict__ n1b,
    const float* __restrict__ n2w, const float* __restrict__ n2b,
    const float* __restrict__ scale,
    float* __restrict__ feats_out, float* __restrict__ coors_out) {
    const int node = blockIdx.x;
    const int b = node >> 10;
    const int t = threadIdx.x;            // edge row 0..127
    const int lane = t & 63, wid = t >> 6;
    const int ln = lane & 15, q = lane >> 4;
    const int rowbase = wid * 64;

    __shared__ __align__(16) float shi[EHP];
    __shared__ __align__(16) float sw65[EHP];
    __shared__ __align__(16) unsigned short smA[2 * 64 * 32];  // swizzled m tiles (per wave)
    __shared__ float sx0[128], sx1[128], su[128], sv[128];
    __shared__ float sgw[DD], se2b[DD], sfi[DD];
    __shared__ float sc1b[128], sc2w[128];
    __shared__ float redm[2][DD], redc[2][2];
    __shared__ float sni[2 * DD], shd[2 * DD];

    for (int u = t; u < EHP; u += 128) {   // strided: EHP > blockDim
        shi[u] = HI[(size_t)node * EHP + u];
        sw65[u] = (u < EH) ? w65[u] : 0.f;
    }
    if (t < DD) { sfi[t] = feats_in[node * DD + t]; sgw[t] = gw[t]; se2b[t] = e2b[t]; }
    sc1b[t] = c1b[t];
    sc2w[t] = c2w[t];
    __syncthreads();

    // ---- per-edge setup (exact fp32, matches reference distance bitwise)
    const float cix = coors_in[node * 2], ciy = coors_in[node * 2 + 1];
    const int j = nbr[(size_t)node * KK + t];
    const float2 cj = *(const float2*)(coors_in + ((size_t)(b * NN) + j) * 2);
    const float dx = cix - cj.x, dy = ciy - cj.y;
    const float rd = __fadd_rn(__fmul_rn(dx, dx), __fmul_rn(dy, dy));
    const float nrm = fmaxf(sqrtf(rd), 1e-8f);
    const float s = scale[0] / nrm;
    su[t] = dx * s;
    sv[t] = dy * s;

    {   // h1 features k=128,129 kept exact fp32 (VALU tail in the e2 epilogue)
        const float2 hjt = *(const float2*)(HJ + ((size_t)(b * NN) + j) * EHP + 128);
        sx0[t] = lrelu(shi[128] + hjt.x + rd * sw65[128]);
        sx1[t] = lrelu(shi[129] + hjt.y + rd * sw65[129]);
    }

    // ---- rows this lane consumes as A-fragments: wave-private -> __shfl
    const float* hjb[4];
    float rdR[4];
#pragma unroll
    for (int mt = 0; mt < 4; mt++) {
        int jR = __shfl(j, mt * 16 + ln, 64);
        rdR[mt] = __shfl(rd, mt * 16 + ln, 64);
        hjb[mt] = HJ + ((size_t)(b * NN) + jR) * EHP;
    }

    const float4* shi4 = (const float4*)shi;
    const float4* sw4  = (const float4*)sw65;

    const f32x4 zz = {0.f, 0.f, 0.f, 0.f};
    f32x4 accA[4][2];
#pragma unroll
    for (int mt = 0; mt < 4; mt++) { accA[mt][0] = zz; accA[mt][1] = zz; }

    // ---- e2 GEMM over K chunks of 32 (k = 0..127), A-frags computed in-register
#pragma unroll 1
    for (int c = 0; c < 4; c++) {
        s16x8 b0 = *(const s16x8*)(e2f + ((c * 2 + 0) * 64 + lane) * 8);
        s16x8 b1 = *(const s16x8*)(e2f + ((c * 2 + 1) * 64 + lane) * 8);
        const int kb = c * 8 + q * 2;               // float4 index of k = 32c + 8q
        const float4 hi0 = shi4[kb], hi1 = shi4[kb + 1];
        const float4 wv0 = sw4[kb],  wv1 = sw4[kb + 1];
#pragma unroll
        for (int mt = 0; mt < 4; mt++) {
            const float4* hjp = (const float4*)(hjb[mt] + c * 32 + q * 8);
            const float4 ha = hjp[0], hb = hjp[1];
            const float r = rdR[mt];
            union { s16x8 v; unsigned u[4]; } A;
            A.u[0] = pk2(lrelu(hi0.x + ha.x + r * wv0.x), lrelu(hi0.y + ha.y + r * wv0.y));
            A.u[1] = pk2(lrelu(hi0.z + ha.z + r * wv0.z), lrelu(hi0.w + ha.w + r * wv0.w));
            A.u[2] = pk2(lrelu(hi1.x + hb.x + r * wv1.x), lrelu(hi1.y + hb.y + r * wv1.y));
            A.u[3] = pk2(lrelu(hi1.z + hb.z + r * wv1.z), lrelu(hi1.w + hb.w + r * wv1.w));
            accA[mt][0] = __builtin_amdgcn_mfma_f32_16x16x32_bf16(A.v, b0, accA[mt][0], 0, 0, 0);
            accA[mt][1] = __builtin_amdgcn_mfma_f32_16x16x32_bf16(A.v, b1, accA[mt][1], 0, 0, 0);
        }
    }

    // ---- e2 epilogue: bias + exact k=128,129 tail + lrelu (C layout)
#pragma unroll
    for (int nt = 0; nt < 2; nt++) {
        const int col = nt * 16 + ln;
        const float w128 = e2w[128 * DD + col];
        const float w129 = e2w[129 * DD + col];
        const float bv = se2b[col];
#pragma unroll
        for (int mt = 0; mt < 4; mt++)
#pragma unroll
            for (int r = 0; r < 4; r++) {
                const int row = rowbase + mt * 16 + q * 4 + r;
                accA[mt][nt][r] = lrelu(accA[mt][nt][r] + bv + sx0[row] * w128 + sx1[row] * w129);
            }
    }

    // ---- soft edge gate (per row; reduce over the 16 col-lanes)
    const float gbv = gb[0];
#pragma unroll
    for (int mt = 0; mt < 4; mt++) {
        float p[4];
#pragma unroll
        for (int r = 0; r < 4; r++)
            p[r] = accA[mt][0][r] * sgw[ln] + accA[mt][1][r] * sgw[16 + ln];
#pragma unroll
        for (int off = 1; off <= 8; off <<= 1)
#pragma unroll
            for (int r = 0; r < 4; r++) p[r] += __shfl_xor(p[r], off);
#pragma unroll
        for (int r = 0; r < 4; r++) {
            const float g = 1.f / (1.f + __expf(-(p[r] + gbv)));
            accA[mt][0][r] *= g;
            accA[mt][1][r] *= g;
        }
    }

    // ---- m_i partials (sum over this wave's 64 rows), fp32 exact m
    float mi0 = 0.f, mi1 = 0.f;
#pragma unroll
    for (int mt = 0; mt < 4; mt++)
#pragma unroll
        for (int r = 0; r < 4; r++) { mi0 += accA[mt][0][r]; mi1 += accA[mt][1][r]; }
    mi0 += __shfl_xor(mi0, 16); mi0 += __shfl_xor(mi0, 32);
    mi1 += __shfl_xor(mi1, 16); mi1 += __shfl_xor(mi1, 32);
    if (lane < 16) { redm[wid][lane] = mi0; redm[wid][16 + lane] = mi1; }

    // ---- m -> swizzled wave-private bf16 tile (write <=2-way, read wire-limited)
    unsigned short* smw = smA + wid * (64 * 32);
#pragma unroll
    for (int mt = 0; mt < 4; mt++)
#pragma unroll
        for (int nt = 0; nt < 2; nt++)
#pragma unroll
            for (int r = 0; r < 4; r++) {
                const int prow = (r << 4) | (4 * mt + q);   // row = 16mt+4q+r
                smw[prow * 32 + nt * 16 + ln] = bf16_hu(accA[mt][nt][r]);
            }

    s16x8 a4[4];
#pragma unroll
    for (int mt = 0; mt < 4; mt++) {
        const int prow = ((ln & 3) << 4) | (4 * mt + (ln >> 2));  // row = 16mt+ln
        a4[mt] = *(const s16x8*)(smw + prow * 32 + q * 8);
    }

    float cacc[4][4];
#pragma unroll
    for (int mt = 0; mt < 4; mt++)
#pragma unroll
        for (int r = 0; r < 4; r++) cacc[mt][r] = 0.f;

#pragma unroll 1
    for (int g = 0; g < 4; g++) {
        s16x8 bc0 = *(const s16x8*)(c1f + ((2 * g + 0) * 64 + lane) * 8);
        s16x8 bc1 = *(const s16x8*)(c1f + ((2 * g + 1) * 64 + lane) * 8);
        f32x4 c20[4], c21[4];
#pragma unroll
        for (int mt = 0; mt < 4; mt++) {
            c20[mt] = __builtin_amdgcn_mfma_f32_16x16x32_bf16(a4[mt], bc0, zz, 0, 0, 0);
            c21[mt] = __builtin_amdgcn_mfma_f32_16x16x32_bf16(a4[mt], bc1, zz, 0, 0, 0);
        }
#pragma unroll
        for (int h = 0; h < 2; h++) {
            const int col = (2 * g + h) * 16 + ln;
            const float c1bv = sc1b[col], c2wv = sc2w[col];
#pragma unroll
            for (int mt = 0; mt < 4; mt++)
#pragma unroll
                for (int r = 0; r < 4; r++) {
                    const float v = (h ? c21[mt][r] : c20[mt][r]) + c1bv;
                    cacc[mt][r] = fmaf(lrelu(v), c2wv, cacc[mt][r]);
                }
        }
    }
#pragma unroll
    for (int off = 1; off <= 8; off <<= 1)
#pragma unroll
        for (int mt = 0; mt < 4; mt++)
#pragma unroll
            for (int r = 0; r < 4; r++) cacc[mt][r] += __shfl_xor(cacc[mt][r], off);

    const float c2bv = c2b[0];
    float vxp = 0.f, vyp = 0.f;
    if (ln == 0) {   // one lane per quad owns its 4 rows
#pragma unroll
        for (int mt = 0; mt < 4; mt++)
#pragma unroll
            for (int r = 0; r < 4; r++) {
                const int row = rowbase + mt * 16 + q * 4 + r;
                const float cw = cacc[mt][r] + c2bv;
                vxp = fmaf(cw, su[row], vxp);
                vyp = fmaf(cw, sv[row], vyp);
            }
    }
    vxp += __shfl_xor(vxp, 16); vxp += __shfl_xor(vxp, 32);
    vyp += __shfl_xor(vyp, 16); vyp += __shfl_xor(vyp, 32);
    if (lane == 0) { redc[wid][0] = vxp; redc[wid][1] = vyp; }

    // ---- cross-wave combine + node MLP + coords
    __syncthreads();
    if (t < DD) {
        sni[t] = sfi[t];
        sni[DD + t] = redm[0][t] + redm[1][t];
    }
    __syncthreads();
    if (t < 2 * DD) {
        float a = n1b[t];
#pragma unroll
        for (int k = 0; k < 2 * DD; k++) a = fmaf(sni[k], n1w[k * 2 * DD + t], a);
        shd[t] = lrelu(a);
    }
    __syncthreads();
    if (t < DD) {
        float a = n2b[t];
#pragma unroll
        for (int o = 0; o < 2 * DD; o++) a = fmaf(shd[o], n2w[o * DD + t], a);
        feats_out[node * DD + t] = a + sfi[t];
    }
    if (t == 0) {
        coors_out[node * 2] = cix + redc[0][0] + redc[1][0];
        coors_out[node * 2 + 1] = ciy + redc[0][1] + redc[1][1];
    }
}

extern "C" void kernel_launch(void* const* d_in, const int* in_sizes, int n_in,
                              void* d_out, int out_size, void* d_ws, size_t ws_size,
                              hipStream_t stream) {
    const float* feat_   = (const float*)d_in[0];
    const float* coor_   = (const float*)d_in[1];
    // d_in[2] = batch (int32, unused: equal-size graphs)
    const float* embed_w = (const float*)d_in[3];
    const float* embed_b = (const float*)d_in[4];
    const float* e1_w    = (const float*)d_in[5];
    const float* e1_b    = (const float*)d_in[6];
    const float* e2_w    = (const float*)d_in[7];
    const float* e2_b    = (const float*)d_in[8];
    const float* gate_w  = (const float*)d_in[9];
    const float* gate_b  = (const float*)d_in[10];
    const float* c1_w    = (const float*)d_in[11];
    const float* c1_b    = (const float*)d_in[12];
    const float* c2_w    = (const float*)d_in[13];
    const float* c2_b    = (const float*)d_in[14];
    const float* n1_w    = (const float*)d_in[15];
    const float* n1_b    = (const float*)d_in[16];
    const float* n2_w    = (const float*)d_in[17];
    const float* n2_b    = (const float*)d_in[18];
    const float* cscale  = (const float*)d_in[19];

    float* ws = (float*)d_ws;
    float* feats_a = ws;               ws += BB * NN * DD;
    float* feats_b = ws;               ws += BB * NN * DD;
    float* coors_a = ws;               ws += BB * NN * 2;
    float* coors_b = ws;               ws += BB * NN * 2;
    float* HI      = ws;               ws += BB * NN * EHP;
    float* HJ      = ws;               ws += BB * NN * EHP;
    unsigned short* e2f = (unsigned short*)ws;   // LL*4096 ushorts
    unsigned short* c1f = e2f + LL * 4096;       // LL*4096 ushorts
    ws += (2 * LL * 4096) / 2;
    int* nbr = (int*)ws;

    embed_kernel<<<(BB * NN * DD + 255) / 256, 256, 0, stream>>>(feat_, embed_w, embed_b, feats_a);
    frag_kernel<<<(2 * LL * 4096 + 255) / 256, 256, 0, stream>>>(e2_w, c1_w, e2f, c1f);

    const float* fin = feats_a;
    const float* cin = coor_;
    float* fouts[LL] = {feats_b, feats_a, (float*)d_out};
    float* couts[LL] = {coors_a, coors_b, coors_a};

    for (int l = 0; l < LL; l++) {
        knn_kernel<<<BB * NN, 256, 0, stream>>>(cin, nbr);
        pre_kernel<<<(BB * NN * EHP + 255) / 256, 256, 0, stream>>>(
            fin, e1_w + (size_t)l * 65 * EH, e1_b + (size_t)l * EH, HI, HJ);
        layer_kernel<<<BB * NN, 128, 0, stream>>>(
            fin, cin, nbr, HI, HJ,
            e1_w + ((size_t)l * 65 + 64) * EH,
            e2_w + (size_t)l * EH * DD,
            e2_b + (size_t)l * DD,
            e2f + (size_t)l * 4096,
            c1f + (size_t)l * 4096,
            gate_w + (size_t)l * DD,
            gate_b + l,
            c1_b + (size_t)l * 128,
            c2_w + (size_t)l * 128,
            c2_b + l,
            n1_w + (size_t)l * 64 * 64,
            n1_b + (size_t)l * 64,
            n2_w + (size_t)l * 64 * 32,
            n2_b + (size_t)l * DD,
            cscale + l,
            fouts[l], couts[l]);
        fin = fouts[l];
        cin = couts[l];
    }
}

// Round 8
// 384.081 us; speedup vs baseline: 2.1824x; 1.0190x over previous
//
#include <hip/hip_runtime.h>
#include <hip/hip_bf16.h>
#include <math.h>

#define BB 4
#define NN 1024
#define KK 128
#define DD 32
#define LL 3
#define EH 130
#define EHP 132

typedef float f32x4 __attribute__((ext_vector_type(4)));
typedef short s16x8 __attribute__((ext_vector_type(8)));

__device__ __forceinline__ float lrelu(float x) { return fmaxf(x, 0.1f * x); }

__device__ __forceinline__ unsigned pk2(float a, float b) {   // v_cvt_pk_bf16_f32 (RNE)
    __hip_bfloat162 h = __float22bfloat162_rn(float2{a, b});
    return *(unsigned*)&h;
}
__device__ __forceinline__ unsigned short bf16_hu(float v) {
    return (unsigned short)((__float_as_uint(v) + 0x8000u) >> 16);
}
__device__ __forceinline__ unsigned short bf16_rne(float v) {
    unsigned u = __float_as_uint(v);
    return (unsigned short)((u + 0x7fffu + ((u >> 16) & 1u)) >> 16);
}

// ---------------- fused: embed (blocks 0..511) + B-fragment precompute (512..607) ----------------
__global__ __launch_bounds__(256) void prep_kernel(
    const float* __restrict__ feat, const float* __restrict__ ew, const float* __restrict__ eb,
    float* __restrict__ out,
    const float* __restrict__ e2w, const float* __restrict__ c1w,
    unsigned short* __restrict__ e2f, unsigned short* __restrict__ c1f) {
    if (blockIdx.x < 512) {
        int t = blockIdx.x * 256 + threadIdx.x;
        if (t >= BB * NN * DD) return;
        int n = t >> 5, o = t & 31;
        const float* f = feat + n * DD;
        float a = eb[o];
#pragma unroll
        for (int k = 0; k < DD; k++) a = fmaf(f[k], ew[k * DD + o], a);
        out[t] = lrelu(a);
    } else {
        int t = (blockIdx.x - 512) * 256 + threadIdx.x;
        if (t < LL * 4 * 2 * 512) {
            int jj = t & 7, lane = (t >> 3) & 63, nt = (t >> 9) & 1, c = (t >> 10) & 3, l = t >> 12;
            int k = 32 * c + (lane >> 4) * 8 + jj;
            int n = nt * 16 + (lane & 15);
            e2f[t] = bf16_rne(e2w[(size_t)l * EH * DD + k * DD + n]);
        } else {
            int u = t - LL * 4 * 2 * 512;
            if (u < LL * 8 * 512) {
                int jj = u & 7, lane = (u >> 3) & 63, nt = (u >> 9) & 7, l = u >> 12;
                int k = (lane >> 4) * 8 + jj;
                int n = nt * 16 + (lane & 15);
                c1f[u] = bf16_rne(c1w[(size_t)l * DD * 128 + k * 128 + n]);
            }
        }
    }
}

// ---------------- fused: KNN radix-select (blocks 0..4095) + HI/HJ precompute (4096..) ----------------
// KNN: exact top-K set matching jax.lax.top_k(-dist,K) incl. lower-index tie-break.
// Fast path: 1 radix pass (wave-shfl scan) -> compact candidates -> O(c) rank.
__global__ __launch_bounds__(256) void knnpre_kernel(
    const float* __restrict__ coors, int* __restrict__ nbr,
    const float* __restrict__ feats, const float* __restrict__ e1w, const float* __restrict__ e1b,
    float* __restrict__ HI, float* __restrict__ HJ) {
    if (blockIdx.x >= BB * NN) {
        // ---- pre part
        int t = (int)(blockIdx.x - BB * NN) * 256 + threadIdx.x;
        if (t >= BB * NN * EHP) return;
        int n = t / EHP, o = t % EHP;
        if (o >= EH) { HI[t] = 0.f; HJ[t] = 0.f; return; }
        const float* f = feats + n * DD;
        float a = e1b[o], c = 0.f;
#pragma unroll
        for (int k = 0; k < DD; k++) a = fmaf(f[k], e1w[k * EH + o], a);
#pragma unroll
        for (int k = 0; k < DD; k++) c = fmaf(f[k], e1w[(DD + k) * EH + o], c);
        HI[t] = a;
        HJ[t] = c;
        return;
    }
    // ---- knn part
    const int node = blockIdx.x;
    const int b = node >> 10, i = node & (NN - 1);
    const int t = threadIdx.x;
    const int lane = t & 63, w = t >> 6;

    __shared__ unsigned cand[NN];      // candidate keys, then tie indices
    __shared__ unsigned hh[256];       // histogram / rare-path reduce
    __shared__ unsigned wsum[4];
    __shared__ unsigned bsel[3];       // {byte, below, bincnt}
    __shared__ unsigned scnt[3];       // {lt slots, eq slots, cand slots}
    __shared__ unsigned sdstar;

    const float2* cb = (const float2*)(coors + (size_t)b * NN * 2);
    const float2 ci = cb[i];
    unsigned k4[4];
#pragma unroll
    for (int c = 0; c < 4; c++) {
        int j = t + c * 256;
        float2 cj = cb[j];
        float dx = ci.x - cj.x, dy = ci.y - cj.y;
        // match numpy per-op rounding exactly (no fma contraction)
        float d = __fadd_rn(__fmul_rn(dx, dx), __fmul_rn(dy, dy));
        k4[c] = __float_as_uint(d);
    }
    if (t < 3) scnt[t] = 0;

    unsigned maskSo = 0u, valSo = 0u;
    unsigned R = KK - 1;               // 0-based rank of the K-th smallest
    unsigned c = NN;
    for (int pass = 0; pass < 4 && c > 256u; pass++) {
        const int shift = 24 - 8 * pass;
        hh[t] = 0;
        __syncthreads();
#pragma unroll
        for (int cc = 0; cc < 4; cc++) {
            unsigned k = k4[cc];
            if ((k & maskSo) == valSo) atomicAdd(&hh[(k >> shift) & 255u], 1u);
        }
        __syncthreads();
        const unsigned mine = hh[t];
        unsigned v = mine;             // wave-level inclusive scan over 64 bins
#pragma unroll
        for (int off = 1; off < 64; off <<= 1) {
            unsigned u = __shfl_up(v, off, 64);
            if (lane >= off) v += u;
        }
        if (lane == 63) wsum[w] = v;
        __syncthreads();
        unsigned pre = 0;
#pragma unroll
        for (int s = 0; s < 3; s++) if (s < w) pre += wsum[s];
        const unsigned cum = v + pre;
        if (R < cum && R >= cum - mine) { bsel[0] = (unsigned)t; bsel[1] = cum - mine; bsel[2] = mine; }
        __syncthreads();
        valSo |= bsel[0] << shift;
        maskSo |= 255u << shift;
        R -= bsel[1];
        c = bsel[2];
        __syncthreads();
    }

    unsigned dstar;
    if (c > 256u) {
        dstar = valSo;                 // 4 passes ran: prefix fully determines the key
    } else {
        // compact candidate keys, rank exactly (serial depth <= c)
#pragma unroll
        for (int cc = 0; cc < 4; cc++) {
            unsigned k = k4[cc];
            if ((k & maskSo) == valSo) {
                unsigned slot = atomicAdd(&scnt[2], 1u);
                cand[slot] = k;
            }
        }
        __syncthreads();
        if (t < (int)c) {
            const unsigned kt = cand[t];
            unsigned less = 0, eq = 0;
            for (unsigned s = 0; s < c; s++) {
                unsigned ks = cand[s];
                less += (ks < kt);
                eq += (ks == kt);
            }
            if (less <= R && R < less + eq) sdstar = kt;
        }
        __syncthreads();
        dstar = sdstar;
    }

    // ---- gather: keys < dstar, then ties (== dstar) by smallest index
#pragma unroll
    for (int cc = 0; cc < 4; cc++) {
        int j = t + cc * 256;
        unsigned k = k4[cc];
        if (k < dstar) {
            unsigned slot = atomicAdd(&scnt[0], 1u);
            nbr[(size_t)node * KK + slot] = j;
        } else if (k == dstar) {
            unsigned slot = atomicAdd(&scnt[1], 1u);
            cand[slot] = (unsigned)j;
        }
    }
    __syncthreads();
    const unsigned base = scnt[0];
    const int E = (int)scnt[1];
    const int need = KK - (int)base;   // >= 1
    if (E == need) {                   // common case
        for (int cc = t; cc < E; cc += 256)
            nbr[(size_t)node * KK + base + cc] = (int)cand[cc];
    } else {                           // rare: pick `need` smallest indices
        for (int r = 0; r < need; r++) {
            unsigned best = 0xFFFFFFFFu;
            for (int cc = t; cc < E; cc += 256) best = min(best, cand[cc]);
            hh[t] = best;
            __syncthreads();
            for (int off = 128; off >= 1; off >>= 1) {
                if (t < off) hh[t] = min(hh[t], hh[t + off]);
                __syncthreads();
            }
            unsigned win = hh[0];
            __syncthreads();
            if (t == 0) nbr[(size_t)node * KK + base + r] = (int)win;
            for (int cc = t; cc < E; cc += 256)
                if (cand[cc] == win) cand[cc] = 0xFFFFFFFFu;
            __syncthreads();
        }
    }
}

// ---------------- fused layer: MFMA e2 + gate + MFMA c1 + reductions + node MLP ----------------
// (unchanged from round 7 — see theory notes there)
__global__ __launch_bounds__(128) void layer_kernel(
    const float* __restrict__ feats_in, const float* __restrict__ coors_in,
    const int*   __restrict__ nbr,
    const float* __restrict__ HI, const float* __restrict__ HJ,
    const float* __restrict__ w65,
    const float* __restrict__ e2w,
    const float* __restrict__ e2b,
    const unsigned short* __restrict__ e2f,
    const unsigned short* __restrict__ c1f,
    const float* __restrict__ gw, const float* __restrict__ gb,
    const float* __restrict__ c1b, const float* __restrict__ c2w, const float* __restrict__ c2b,
    const float* __restrict__ n1w, const float* __restrict__ n1b,
    const float* __restrict__ n2w, const float* __restrict__ n2b,
    const float* __restrict__ scale,
    float* __restrict__ feats_out, float* __restrict__ coors_out) {
    const int node = blockIdx.x;
    const int b = node >> 10;
    const int t = threadIdx.x;
    const int lane = t & 63, wid = t >> 6;
    const int ln = lane & 15, q = lane >> 4;
    const int rowbase = wid * 64;

    __shared__ __align__(16) float shi[EHP];
    __shared__ __align__(16) float sw65[EHP];
    __shared__ __align__(16) unsigned short smA[2 * 64 * 32];
    __shared__ float sx0[128], sx1[128], su[128], sv[128];
    __shared__ float sgw[DD], se2b[DD], sfi[DD];
    __shared__ float sc1b[128], sc2w[128];
    __shared__ float redm[2][DD], redc[2][2];
    __shared__ float sni[2 * DD], shd[2 * DD];

    for (int u = t; u < EHP; u += 128) {
        shi[u] = HI[(size_t)node * EHP + u];
        sw65[u] = (u < EH) ? w65[u] : 0.f;
    }
    if (t < DD) { sfi[t] = feats_in[node * DD + t]; sgw[t] = gw[t]; se2b[t] = e2b[t]; }
    sc1b[t] = c1b[t];
    sc2w[t] = c2w[t];
    __syncthreads();

    const float cix = coors_in[node * 2], ciy = coors_in[node * 2 + 1];
    const int j = nbr[(size_t)node * KK + t];
    const float2 cj = *(const float2*)(coors_in + ((size_t)(b * NN) + j) * 2);
    const float dx = cix - cj.x, dy = ciy - cj.y;
    const float rd = __fadd_rn(__fmul_rn(dx, dx), __fmul_rn(dy, dy));
    const float nrm = fmaxf(sqrtf(rd), 1e-8f);
    const float s = scale[0] / nrm;
    su[t] = dx * s;
    sv[t] = dy * s;

    {
        const float2 hjt = *(const float2*)(HJ + ((size_t)(b * NN) + j) * EHP + 128);
        sx0[t] = lrelu(shi[128] + hjt.x + rd * sw65[128]);
        sx1[t] = lrelu(shi[129] + hjt.y + rd * sw65[129]);
    }

    const float* hjb[4];
    float rdR[4];
#pragma unroll
    for (int mt = 0; mt < 4; mt++) {
        int jR = __shfl(j, mt * 16 + ln, 64);
        rdR[mt] = __shfl(rd, mt * 16 + ln, 64);
        hjb[mt] = HJ + ((size_t)(b * NN) + jR) * EHP;
    }

    const float4* shi4 = (const float4*)shi;
    const float4* sw4  = (const float4*)sw65;

    const f32x4 zz = {0.f, 0.f, 0.f, 0.f};
    f32x4 accA[4][2];
#pragma unroll
    for (int mt = 0; mt < 4; mt++) { accA[mt][0] = zz; accA[mt][1] = zz; }

#pragma unroll 1
    for (int c = 0; c < 4; c++) {
        s16x8 b0 = *(const s16x8*)(e2f + ((c * 2 + 0) * 64 + lane) * 8);
        s16x8 b1 = *(const s16x8*)(e2f + ((c * 2 + 1) * 64 + lane) * 8);
        const int kb = c * 8 + q * 2;
        const float4 hi0 = shi4[kb], hi1 = shi4[kb + 1];
        const float4 wv0 = sw4[kb],  wv1 = sw4[kb + 1];
#pragma unroll
        for (int mt = 0; mt < 4; mt++) {
            const float4* hjp = (const float4*)(hjb[mt] + c * 32 + q * 8);
            const float4 ha = hjp[0], hb = hjp[1];
            const float r = rdR[mt];
            union { s16x8 v; unsigned u[4]; } A;
            A.u[0] = pk2(lrelu(hi0.x + ha.x + r * wv0.x), lrelu(hi0.y + ha.y + r * wv0.y));
            A.u[1] = pk2(lrelu(hi0.z + ha.z + r * wv0.z), lrelu(hi0.w + ha.w + r * wv0.w));
            A.u[2] = pk2(lrelu(hi1.x + hb.x + r * wv1.x), lrelu(hi1.y + hb.y + r * wv1.y));
            A.u[3] = pk2(lrelu(hi1.z + hb.z + r * wv1.z), lrelu(hi1.w + hb.w + r * wv1.w));
            accA[mt][0] = __builtin_amdgcn_mfma_f32_16x16x32_bf16(A.v, b0, accA[mt][0], 0, 0, 0);
            accA[mt][1] = __builtin_amdgcn_mfma_f32_16x16x32_bf16(A.v, b1, accA[mt][1], 0, 0, 0);
        }
    }

#pragma unroll
    for (int nt = 0; nt < 2; nt++) {
        const int col = nt * 16 + ln;
        const float w128 = e2w[128 * DD + col];
        const float w129 = e2w[129 * DD + col];
        const float bv = se2b[col];
#pragma unroll
        for (int mt = 0; mt < 4; mt++)
#pragma unroll
            for (int r = 0; r < 4; r++) {
                const int row = rowbase + mt * 16 + q * 4 + r;
                accA[mt][nt][r] = lrelu(accA[mt][nt][r] + bv + sx0[row] * w128 + sx1[row] * w129);
            }
    }

    const float gbv = gb[0];
#pragma unroll
    for (int mt = 0; mt < 4; mt++) {
        float p[4];
#pragma unroll
        for (int r = 0; r < 4; r++)
            p[r] = accA[mt][0][r] * sgw[ln] + accA[mt][1][r] * sgw[16 + ln];
#pragma unroll
        for (int off = 1; off <= 8; off <<= 1)
#pragma unroll
            for (int r = 0; r < 4; r++) p[r] += __shfl_xor(p[r], off);
#pragma unroll
        for (int r = 0; r < 4; r++) {
            const float g = 1.f / (1.f + __expf(-(p[r] + gbv)));
            accA[mt][0][r] *= g;
            accA[mt][1][r] *= g;
        }
    }

    float mi0 = 0.f, mi1 = 0.f;
#pragma unroll
    for (int mt = 0; mt < 4; mt++)
#pragma unroll
        for (int r = 0; r < 4; r++) { mi0 += accA[mt][0][r]; mi1 += accA[mt][1][r]; }
    mi0 += __shfl_xor(mi0, 16); mi0 += __shfl_xor(mi0, 32);
    mi1 += __shfl_xor(mi1, 16); mi1 += __shfl_xor(mi1, 32);
    if (lane < 16) { redm[wid][lane] = mi0; redm[wid][16 + lane] = mi1; }

    unsigned short* smw = smA + wid * (64 * 32);
#pragma unroll
    for (int mt = 0; mt < 4; mt++)
#pragma unroll
        for (int nt = 0; nt < 2; nt++)
#pragma unroll
            for (int r = 0; r < 4; r++) {
                const int prow = (r << 4) | (4 * mt + q);
                smw[prow * 32 + nt * 16 + ln] = bf16_hu(accA[mt][nt][r]);
            }

    s16x8 a4[4];
#pragma unroll
    for (int mt = 0; mt < 4; mt++) {
        const int prow = ((ln & 3) << 4) | (4 * mt + (ln >> 2));
        a4[mt] = *(const s16x8*)(smw + prow * 32 + q * 8);
    }

    float cacc[4][4];
#pragma unroll
    for (int mt = 0; mt < 4; mt++)
#pragma unroll
        for (int r = 0; r < 4; r++) cacc[mt][r] = 0.f;

#pragma unroll 1
    for (int g = 0; g < 4; g++) {
        s16x8 bc0 = *(const s16x8*)(c1f + ((2 * g + 0) * 64 + lane) * 8);
        s16x8 bc1 = *(const s16x8*)(c1f + ((2 * g + 1) * 64 + lane) * 8);
        f32x4 c20[4], c21[4];
#pragma unroll
        for (int mt = 0; mt < 4; mt++) {
            c20[mt] = __builtin_amdgcn_mfma_f32_16x16x32_bf16(a4[mt], bc0, zz, 0, 0, 0);
            c21[mt] = __builtin_amdgcn_mfma_f32_16x16x32_bf16(a4[mt], bc1, zz, 0, 0, 0);
        }
#pragma unroll
        for (int h = 0; h < 2; h++) {
            const int col = (2 * g + h) * 16 + ln;
            const float c1bv = sc1b[col], c2wv = sc2w[col];
#pragma unroll
            for (int mt = 0; mt < 4; mt++)
#pragma unroll
                for (int r = 0; r < 4; r++) {
                    const float v = (h ? c21[mt][r] : c20[mt][r]) + c1bv;
                    cacc[mt][r] = fmaf(lrelu(v), c2wv, cacc[mt][r]);
                }
        }
    }
#pragma unroll
    for (int off = 1; off <= 8; off <<= 1)
#pragma unroll
        for (int mt = 0; mt < 4; mt++)
#pragma unroll
            for (int r = 0; r < 4; r++) cacc[mt][r] += __shfl_xor(cacc[mt][r], off);

    const float c2bv = c2b[0];
    float vxp = 0.f, vyp = 0.f;
    if (ln == 0) {
#pragma unroll
        for (int mt = 0; mt < 4; mt++)
#pragma unroll
            for (int r = 0; r < 4; r++) {
                const int row = rowbase + mt * 16 + q * 4 + r;
                const float cw = cacc[mt][r] + c2bv;
                vxp = fmaf(cw, su[row], vxp);
                vyp = fmaf(cw, sv[row], vyp);
            }
    }
    vxp += __shfl_xor(vxp, 16); vxp += __shfl_xor(vxp, 32);
    vyp += __shfl_xor(vyp, 16); vyp += __shfl_xor(vyp, 32);
    if (lane == 0) { redc[wid][0] = vxp; redc[wid][1] = vyp; }

    __syncthreads();
    if (t < DD) {
        sni[t] = sfi[t];
        sni[DD + t] = redm[0][t] + redm[1][t];
    }
    __syncthreads();
    if (t < 2 * DD) {
        float a = n1b[t];
#pragma unroll
        for (int k = 0; k < 2 * DD; k++) a = fmaf(sni[k], n1w[k * 2 * DD + t], a);
        shd[t] = lrelu(a);
    }
    __syncthreads();
    if (t < DD) {
        float a = n2b[t];
#pragma unroll
        for (int o = 0; o < 2 * DD; o++) a = fmaf(shd[o], n2w[o * DD + t], a);
        feats_out[node * DD + t] = a + sfi[t];
    }
    if (t == 0) {
        coors_out[node * 2] = cix + redc[0][0] + redc[1][0];
        coors_out[node * 2 + 1] = ciy + redc[0][1] + redc[1][1];
    }
}

extern "C" void kernel_launch(void* const* d_in, const int* in_sizes, int n_in,
                              void* d_out, int out_size, void* d_ws, size_t ws_size,
                              hipStream_t stream) {
    const float* feat_   = (const float*)d_in[0];
    const float* coor_   = (const float*)d_in[1];
    // d_in[2] = batch (int32, unused: equal-size graphs)
    const float* embed_w = (const float*)d_in[3];
    const float* embed_b = (const float*)d_in[4];
    const float* e1_w    = (const float*)d_in[5];
    const float* e1_b    = (const float*)d_in[6];
    const float* e2_w    = (const float*)d_in[7];
    const float* e2_b    = (const float*)d_in[8];
    const float* gate_w  = (const float*)d_in[9];
    const float* gate_b  = (const float*)d_in[10];
    const float* c1_w    = (const float*)d_in[11];
    const float* c1_b    = (const float*)d_in[12];
    const float* c2_w    = (const float*)d_in[13];
    const float* c2_b    = (const float*)d_in[14];
    const float* n1_w    = (const float*)d_in[15];
    const float* n1_b    = (const float*)d_in[16];
    const float* n2_w    = (const float*)d_in[17];
    const float* n2_b    = (const float*)d_in[18];
    const float* cscale  = (const float*)d_in[19];

    float* ws = (float*)d_ws;
    float* feats_a = ws;               ws += BB * NN * DD;
    float* feats_b = ws;               ws += BB * NN * DD;
    float* coors_a = ws;               ws += BB * NN * 2;
    float* coors_b = ws;               ws += BB * NN * 2;
    float* HI      = ws;               ws += BB * NN * EHP;
    float* HJ      = ws;               ws += BB * NN * EHP;
    unsigned short* e2f = (unsigned short*)ws;   // LL*4096 ushorts
    unsigned short* c1f = e2f + LL * 4096;       // LL*4096 ushorts
    ws += (2 * LL * 4096) / 2;
    int* nbr = (int*)ws;

    prep_kernel<<<512 + 96, 256, 0, stream>>>(feat_, embed_w, embed_b, feats_a,
                                              e2_w, c1_w, e2f, c1f);

    const int PREB = (BB * NN * EHP + 255) / 256;   // 2112
    const float* fin = feats_a;
    const float* cin = coor_;
    float* fouts[LL] = {feats_b, feats_a, (float*)d_out};
    float* couts[LL] = {coors_a, coors_b, coors_a};

    for (int l = 0; l < LL; l++) {
        knnpre_kernel<<<BB * NN + PREB, 256, 0, stream>>>(
            cin, nbr, fin, e1_w + (size_t)l * 65 * EH, e1_b + (size_t)l * EH, HI, HJ);
        layer_kernel<<<BB * NN, 128, 0, stream>>>(
            fin, cin, nbr, HI, HJ,
            e1_w + ((size_t)l * 65 + 64) * EH,
            e2_w + (size_t)l * EH * DD,
            e2_b + (size_t)l * DD,
            e2f + (size_t)l * 4096,
            c1f + (size_t)l * 4096,
            gate_w + (size_t)l * DD,
            gate_b + l,
            c1_b + (size_t)l * 128,
            c2_w + (size_t)l * 128,
            c2_b + l,
            n1_w + (size_t)l * 64 * 64,
            n1_b + (size_t)l * 64,
            n2_w + (size_t)l * 64 * 32,
            n2_b + (size_t)l * DD,
            cscale + l,
            fouts[l], couts[l]);
        fin = fouts[l];
        cin = couts[l];
    }
}

// Round 9
// 362.286 us; speedup vs baseline: 2.3137x; 1.0602x over previous
//
#include <hip/hip_runtime.h>
#include <hip/hip_bf16.h>
#include <math.h>

#define BB 4
#define NN 1024
#define KK 128
#define DD 32
#define LL 3
#define EH 130
#define EHP 132

typedef float f32x4 __attribute__((ext_vector_type(4)));
typedef short s16x8 __attribute__((ext_vector_type(8)));

__device__ __forceinline__ float lrelu(float x) { return fmaxf(x, 0.1f * x); }

__device__ __forceinline__ unsigned pk2(float a, float b) {   // v_cvt_pk_bf16_f32 (RNE)
    __hip_bfloat162 h = __float22bfloat162_rn(float2{a, b});
    return *(unsigned*)&h;
}
__device__ __forceinline__ unsigned short bf16_hu(float v) {
    return (unsigned short)((__float_as_uint(v) + 0x8000u) >> 16);
}
__device__ __forceinline__ unsigned short bf16_rne(float v) {
    unsigned u = __float_as_uint(v);
    return (unsigned short)((u + 0x7fffu + ((u >> 16) & 1u)) >> 16);
}

// ---------------- fused: embed (blocks 0..511) + B-fragment precompute (512..607) ----------------
__global__ __launch_bounds__(256) void prep_kernel(
    const float* __restrict__ feat, const float* __restrict__ ew, const float* __restrict__ eb,
    float* __restrict__ out,
    const float* __restrict__ e2w, const float* __restrict__ c1w,
    unsigned short* __restrict__ e2f, unsigned short* __restrict__ c1f) {
    if (blockIdx.x < 512) {
        int t = blockIdx.x * 256 + threadIdx.x;
        if (t >= BB * NN * DD) return;
        int n = t >> 5, o = t & 31;
        const float* f = feat + n * DD;
        float a = eb[o];
#pragma unroll
        for (int k = 0; k < DD; k++) a = fmaf(f[k], ew[k * DD + o], a);
        out[t] = lrelu(a);
    } else {
        int t = (blockIdx.x - 512) * 256 + threadIdx.x;
        if (t < LL * 4 * 2 * 512) {
            int jj = t & 7, lane = (t >> 3) & 63, nt = (t >> 9) & 1, c = (t >> 10) & 3, l = t >> 12;
            int k = 32 * c + (lane >> 4) * 8 + jj;
            int n = nt * 16 + (lane & 15);
            e2f[t] = bf16_rne(e2w[(size_t)l * EH * DD + k * DD + n]);
        } else {
            int u = t - LL * 4 * 2 * 512;
            if (u < LL * 8 * 512) {
                int jj = u & 7, lane = (u >> 3) & 63, nt = (u >> 9) & 7, l = u >> 12;
                int k = (lane >> 4) * 8 + jj;
                int n = nt * 16 + (lane & 15);
                c1f[u] = bf16_rne(c1w[(size_t)l * DD * 128 + k * 128 + n]);
            }
        }
    }
}

// ---------------- fused: wave-per-node KNN (blocks 0..1023) + HI/HJ precompute ----------------
// KNN: exact top-K set matching jax.lax.top_k(-dist,K) incl. lower-index tie-break.
// One wave per node; 16 keys/lane in VGPRs; dstar via 31-step MSB-first binary
// search on uint32 distance bits (d>=0 -> uint order == float order). No LDS, no barriers.
__global__ __launch_bounds__(256) void knnpre_kernel(
    const float* __restrict__ coors, int* __restrict__ nbr,
    const float* __restrict__ feats, const float* __restrict__ e1w, const float* __restrict__ e1b,
    float* __restrict__ HI, float* __restrict__ HJ) {
    const int KNNB = BB * NN / 4;      // 1024 blocks, 4 waves each
    if (blockIdx.x >= KNNB) {
        // ---- pre part
        int t = (int)(blockIdx.x - KNNB) * 256 + threadIdx.x;
        if (t >= BB * NN * EHP) return;
        int n = t / EHP, o = t % EHP;
        if (o >= EH) { HI[t] = 0.f; HJ[t] = 0.f; return; }
        const float* f = feats + n * DD;
        float a = e1b[o], c = 0.f;
#pragma unroll
        for (int k = 0; k < DD; k++) a = fmaf(f[k], e1w[k * EH + o], a);
#pragma unroll
        for (int k = 0; k < DD; k++) c = fmaf(f[k], e1w[(DD + k) * EH + o], c);
        HI[t] = a;
        HJ[t] = c;
        return;
    }
    // ---- knn part: node = 4*blockIdx + waveId
    const int node = (int)blockIdx.x * 4 + (threadIdx.x >> 6);
    const int b = node >> 10, i = node & (NN - 1);
    const int lane = threadIdx.x & 63;

    const float2* cb = (const float2*)(coors + (size_t)b * NN * 2);
    const float2 ci = cb[i];
    unsigned k[16];
#pragma unroll
    for (int s = 0; s < 16; s++) {
        float2 cj = cb[lane + 64 * s];
        float dx = ci.x - cj.x, dy = ci.y - cj.y;
        // match numpy per-op rounding exactly (no fma contraction)
        float d = __fadd_rn(__fmul_rn(dx, dx), __fmul_rn(dy, dy));
        k[s] = __float_as_uint(d);
    }

    // dstar = 128th smallest (sorted[127]): bitwise construction, invariant
    // dstar in [P, P + 2^(bpos+1)). count(keys < P|2^bpos) >= 128 <=> sorted[127] < P|2^bpos.
    unsigned P = 0;
    for (int bpos = 30; bpos >= 0; bpos--) {
        const unsigned X = P | (1u << bpos);
        unsigned c = 0;
#pragma unroll
        for (int s = 0; s < 16; s++) c += (k[s] < X) ? 1u : 0u;
#pragma unroll
        for (int off = 1; off < 64; off <<= 1) c += __shfl_xor(c, off, 64);
        if (c < (unsigned)KK) P = X;   // bit is 1; else bit stays 0
    }
    const unsigned dstar = P;

    // gather keys < dstar: exclusive prefix over per-lane counts
    unsigned myc = 0;
#pragma unroll
    for (int s = 0; s < 16; s++) myc += (k[s] < dstar) ? 1u : 0u;
    unsigned inc = myc;
#pragma unroll
    for (int off = 1; off < 64; off <<= 1) {
        unsigned u = __shfl_up(inc, off, 64);
        if (lane >= off) inc += u;
    }
    unsigned pos = inc - myc;
    const unsigned total_less = __shfl(inc, 63, 64);
    int* nb = nbr + (size_t)node * KK;
#pragma unroll
    for (int s = 0; s < 16; s++)
        if (k[s] < dstar) nb[pos++] = lane + 64 * s;

    // ties (== dstar) in ascending index order until K filled
    const int need = KK - (int)total_less;   // >= 1
    unsigned tie_so_far = 0;
    for (int s = 0; s < 16 && (int)tie_so_far < need; s++) {
        unsigned long long mask = __ballot(k[s] == dstar);
        if (k[s] == dstar) {
            unsigned r = tie_so_far + (unsigned)__popcll(mask & ((1ull << lane) - 1ull));
            if ((int)r < need) nb[total_less + r] = lane + 64 * s;
        }
        tie_so_far += (unsigned)__popcll(mask);
    }
}

// ---------------- fused layer: MFMA e2 + gate + MFMA c1 + reductions + node MLP ----------------
// (unchanged from round 7 — see theory notes there)
__global__ __launch_bounds__(128) void layer_kernel(
    const float* __restrict__ feats_in, const float* __restrict__ coors_in,
    const int*   __restrict__ nbr,
    const float* __restrict__ HI, const float* __restrict__ HJ,
    const float* __restrict__ w65,
    const float* __restrict__ e2w,
    const float* __restrict__ e2b,
    const unsigned short* __restrict__ e2f,
    const unsigned short* __restrict__ c1f,
    const float* __restrict__ gw, const float* __restrict__ gb,
    const float* __restrict__ c1b, const float* __restrict__ c2w, const float* __restrict__ c2b,
    const float* __restrict__ n1w, const float* __restrict__ n1b,
    const float* __restrict__ n2w, const float* __restrict__ n2b,
    const float* __restrict__ scale,
    float* __restrict__ feats_out, float* __restrict__ coors_out) {
    const int node = blockIdx.x;
    const int b = node >> 10;
    const int t = threadIdx.x;
    const int lane = t & 63, wid = t >> 6;
    const int ln = lane & 15, q = lane >> 4;
    const int rowbase = wid * 64;

    __shared__ __align__(16) float shi[EHP];
    __shared__ __align__(16) float sw65[EHP];
    __shared__ __align__(16) unsigned short smA[2 * 64 * 32];
    __shared__ float sx0[128], sx1[128], su[128], sv[128];
    __shared__ float sgw[DD], se2b[DD], sfi[DD];
    __shared__ float sc1b[128], sc2w[128];
    __shared__ float redm[2][DD], redc[2][2];
    __shared__ float sni[2 * DD], shd[2 * DD];

    for (int u = t; u < EHP; u += 128) {
        shi[u] = HI[(size_t)node * EHP + u];
        sw65[u] = (u < EH) ? w65[u] : 0.f;
    }
    if (t < DD) { sfi[t] = feats_in[node * DD + t]; sgw[t] = gw[t]; se2b[t] = e2b[t]; }
    sc1b[t] = c1b[t];
    sc2w[t] = c2w[t];
    __syncthreads();

    const float cix = coors_in[node * 2], ciy = coors_in[node * 2 + 1];
    const int j = nbr[(size_t)node * KK + t];
    const float2 cj = *(const float2*)(coors_in + ((size_t)(b * NN) + j) * 2);
    const float dx = cix - cj.x, dy = ciy - cj.y;
    const float rd = __fadd_rn(__fmul_rn(dx, dx), __fmul_rn(dy, dy));
    const float nrm = fmaxf(sqrtf(rd), 1e-8f);
    const float s = scale[0] / nrm;
    su[t] = dx * s;
    sv[t] = dy * s;

    {
        const float2 hjt = *(const float2*)(HJ + ((size_t)(b * NN) + j) * EHP + 128);
        sx0[t] = lrelu(shi[128] + hjt.x + rd * sw65[128]);
        sx1[t] = lrelu(shi[129] + hjt.y + rd * sw65[129]);
    }

    const float* hjb[4];
    float rdR[4];
#pragma unroll
    for (int mt = 0; mt < 4; mt++) {
        int jR = __shfl(j, mt * 16 + ln, 64);
        rdR[mt] = __shfl(rd, mt * 16 + ln, 64);
        hjb[mt] = HJ + ((size_t)(b * NN) + jR) * EHP;
    }

    const float4* shi4 = (const float4*)shi;
    const float4* sw4  = (const float4*)sw65;

    const f32x4 zz = {0.f, 0.f, 0.f, 0.f};
    f32x4 accA[4][2];
#pragma unroll
    for (int mt = 0; mt < 4; mt++) { accA[mt][0] = zz; accA[mt][1] = zz; }

#pragma unroll 1
    for (int c = 0; c < 4; c++) {
        s16x8 b0 = *(const s16x8*)(e2f + ((c * 2 + 0) * 64 + lane) * 8);
        s16x8 b1 = *(const s16x8*)(e2f + ((c * 2 + 1) * 64 + lane) * 8);
        const int kb = c * 8 + q * 2;
        const float4 hi0 = shi4[kb], hi1 = shi4[kb + 1];
        const float4 wv0 = sw4[kb],  wv1 = sw4[kb + 1];
#pragma unroll
        for (int mt = 0; mt < 4; mt++) {
            const float4* hjp = (const float4*)(hjb[mt] + c * 32 + q * 8);
            const float4 ha = hjp[0], hb = hjp[1];
            const float r = rdR[mt];
            union { s16x8 v; unsigned u[4]; } A;
            A.u[0] = pk2(lrelu(hi0.x + ha.x + r * wv0.x), lrelu(hi0.y + ha.y + r * wv0.y));
            A.u[1] = pk2(lrelu(hi0.z + ha.z + r * wv0.z), lrelu(hi0.w + ha.w + r * wv0.w));
            A.u[2] = pk2(lrelu(hi1.x + hb.x + r * wv1.x), lrelu(hi1.y + hb.y + r * wv1.y));
            A.u[3] = pk2(lrelu(hi1.z + hb.z + r * wv1.z), lrelu(hi1.w + hb.w + r * wv1.w));
            accA[mt][0] = __builtin_amdgcn_mfma_f32_16x16x32_bf16(A.v, b0, accA[mt][0], 0, 0, 0);
            accA[mt][1] = __builtin_amdgcn_mfma_f32_16x16x32_bf16(A.v, b1, accA[mt][1], 0, 0, 0);
        }
    }

#pragma unroll
    for (int nt = 0; nt < 2; nt++) {
        const int col = nt * 16 + ln;
        const float w128 = e2w[128 * DD + col];
        const float w129 = e2w[129 * DD + col];
        const float bv = se2b[col];
#pragma unroll
        for (int mt = 0; mt < 4; mt++)
#pragma unroll
            for (int r = 0; r < 4; r++) {
                const int row = rowbase + mt * 16 + q * 4 + r;
                accA[mt][nt][r] = lrelu(accA[mt][nt][r] + bv + sx0[row] * w128 + sx1[row] * w129);
            }
    }

    const float gbv = gb[0];
#pragma unroll
    for (int mt = 0; mt < 4; mt++) {
        float p[4];
#pragma unroll
        for (int r = 0; r < 4; r++)
            p[r] = accA[mt][0][r] * sgw[ln] + accA[mt][1][r] * sgw[16 + ln];
#pragma unroll
        for (int off = 1; off <= 8; off <<= 1)
#pragma unroll
            for (int r = 0; r < 4; r++) p[r] += __shfl_xor(p[r], off);
#pragma unroll
        for (int r = 0; r < 4; r++) {
            const float g = 1.f / (1.f + __expf(-(p[r] + gbv)));
            accA[mt][0][r] *= g;
            accA[mt][1][r] *= g;
        }
    }

    float mi0 = 0.f, mi1 = 0.f;
#pragma unroll
    for (int mt = 0; mt < 4; mt++)
#pragma unroll
        for (int r = 0; r < 4; r++) { mi0 += accA[mt][0][r]; mi1 += accA[mt][1][r]; }
    mi0 += __shfl_xor(mi0, 16); mi0 += __shfl_xor(mi0, 32);
    mi1 += __shfl_xor(mi1, 16); mi1 += __shfl_xor(mi1, 32);
    if (lane < 16) { redm[wid][lane] = mi0; redm[wid][16 + lane] = mi1; }

    unsigned short* smw = smA + wid * (64 * 32);
#pragma unroll
    for (int mt = 0; mt < 4; mt++)
#pragma unroll
        for (int nt = 0; nt < 2; nt++)
#pragma unroll
            for (int r = 0; r < 4; r++) {
                const int prow = (r << 4) | (4 * mt + q);
                smw[prow * 32 + nt * 16 + ln] = bf16_hu(accA[mt][nt][r]);
            }

    s16x8 a4[4];
#pragma unroll
    for (int mt = 0; mt < 4; mt++) {
        const int prow = ((ln & 3) << 4) | (4 * mt + (ln >> 2));
        a4[mt] = *(const s16x8*)(smw + prow * 32 + q * 8);
    }

    float cacc[4][4];
#pragma unroll
    for (int mt = 0; mt < 4; mt++)
#pragma unroll
        for (int r = 0; r < 4; r++) cacc[mt][r] = 0.f;

#pragma unroll 1
    for (int g = 0; g < 4; g++) {
        s16x8 bc0 = *(const s16x8*)(c1f + ((2 * g + 0) * 64 + lane) * 8);
        s16x8 bc1 = *(const s16x8*)(c1f + ((2 * g + 1) * 64 + lane) * 8);
        f32x4 c20[4], c21[4];
#pragma unroll
        for (int mt = 0; mt < 4; mt++) {
            c20[mt] = __builtin_amdgcn_mfma_f32_16x16x32_bf16(a4[mt], bc0, zz, 0, 0, 0);
            c21[mt] = __builtin_amdgcn_mfma_f32_16x16x32_bf16(a4[mt], bc1, zz, 0, 0, 0);
        }
#pragma unroll
        for (int h = 0; h < 2; h++) {
            const int col = (2 * g + h) * 16 + ln;
            const float c1bv = sc1b[col], c2wv = sc2w[col];
#pragma unroll
            for (int mt = 0; mt < 4; mt++)
#pragma unroll
                for (int r = 0; r < 4; r++) {
                    const float v = (h ? c21[mt][r] : c20[mt][r]) + c1bv;
                    cacc[mt][r] = fmaf(lrelu(v), c2wv, cacc[mt][r]);
                }
        }
    }
#pragma unroll
    for (int off = 1; off <= 8; off <<= 1)
#pragma unroll
        for (int mt = 0; mt < 4; mt++)
#pragma unroll
            for (int r = 0; r < 4; r++) cacc[mt][r] += __shfl_xor(cacc[mt][r], off);

    const float c2bv = c2b[0];
    float vxp = 0.f, vyp = 0.f;
    if (ln == 0) {
#pragma unroll
        for (int mt = 0; mt < 4; mt++)
#pragma unroll
            for (int r = 0; r < 4; r++) {
                const int row = rowbase + mt * 16 + q * 4 + r;
                const float cw = cacc[mt][r] + c2bv;
                vxp = fmaf(cw, su[row], vxp);
                vyp = fmaf(cw, sv[row], vyp);
            }
    }
    vxp += __shfl_xor(vxp, 16); vxp += __shfl_xor(vxp, 32);
    vyp += __shfl_xor(vyp, 16); vyp += __shfl_xor(vyp, 32);
    if (lane == 0) { redc[wid][0] = vxp; redc[wid][1] = vyp; }

    __syncthreads();
    if (t < DD) {
        sni[t] = sfi[t];
        sni[DD + t] = redm[0][t] + redm[1][t];
    }
    __syncthreads();
    if (t < 2 * DD) {
        float a = n1b[t];
#pragma unroll
        for (int k = 0; k < 2 * DD; k++) a = fmaf(sni[k], n1w[k * 2 * DD + t], a);
        shd[t] = lrelu(a);
    }
    __syncthreads();
    if (t < DD) {
        float a = n2b[t];
#pragma unroll
        for (int o = 0; o < 2 * DD; o++) a = fmaf(shd[o], n2w[o * DD + t], a);
        feats_out[node * DD + t] = a + sfi[t];
    }
    if (t == 0) {
        coors_out[node * 2] = cix + redc[0][0] + redc[1][0];
        coors_out[node * 2 + 1] = ciy + redc[0][1] + redc[1][1];
    }
}

extern "C" void kernel_launch(void* const* d_in, const int* in_sizes, int n_in,
                              void* d_out, int out_size, void* d_ws, size_t ws_size,
                              hipStream_t stream) {
    const float* feat_   = (const float*)d_in[0];
    const float* coor_   = (const float*)d_in[1];
    // d_in[2] = batch (int32, unused: equal-size graphs)
    const float* embed_w = (const float*)d_in[3];
    const float* embed_b = (const float*)d_in[4];
    const float* e1_w    = (const float*)d_in[5];
    const float* e1_b    = (const float*)d_in[6];
    const float* e2_w    = (const float*)d_in[7];
    const float* e2_b    = (const float*)d_in[8];
    const float* gate_w  = (const float*)d_in[9];
    const float* gate_b  = (const float*)d_in[10];
    const float* c1_w    = (const float*)d_in[11];
    const float* c1_b    = (const float*)d_in[12];
    const float* c2_w    = (const float*)d_in[13];
    const float* c2_b    = (const float*)d_in[14];
    const float* n1_w    = (const float*)d_in[15];
    const float* n1_b    = (const float*)d_in[16];
    const float* n2_w    = (const float*)d_in[17];
    const float* n2_b    = (const float*)d_in[18];
    const float* cscale  = (const float*)d_in[19];

    float* ws = (float*)d_ws;
    float* feats_a = ws;               ws += BB * NN * DD;
    float* feats_b = ws;               ws += BB * NN * DD;
    float* coors_a = ws;               ws += BB * NN * 2;
    float* coors_b = ws;               ws += BB * NN * 2;
    float* HI      = ws;               ws += BB * NN * EHP;
    float* HJ      = ws;               ws += BB * NN * EHP;
    unsigned short* e2f = (unsigned short*)ws;   // LL*4096 ushorts
    unsigned short* c1f = e2f + LL * 4096;       // LL*4096 ushorts
    ws += (2 * LL * 4096) / 2;
    int* nbr = (int*)ws;

    prep_kernel<<<512 + 96, 256, 0, stream>>>(feat_, embed_w, embed_b, feats_a,
                                              e2_w, c1_w, e2f, c1f);

    const int KNNB = BB * NN / 4;                   // 1024
    const int PREB = (BB * NN * EHP + 255) / 256;   // 2112
    const float* fin = feats_a;
    const float* cin = coor_;
    float* fouts[LL] = {feats_b, feats_a, (float*)d_out};
    float* couts[LL] = {coors_a, coors_b, coors_a};

    for (int l = 0; l < LL; l++) {
        knnpre_kernel<<<KNNB + PREB, 256, 0, stream>>>(
            cin, nbr, fin, e1_w + (size_t)l * 65 * EH, e1_b + (size_t)l * EH, HI, HJ);
        layer_kernel<<<BB * NN, 128, 0, stream>>>(
            fin, cin, nbr, HI, HJ,
            e1_w + ((size_t)l * 65 + 64) * EH,
            e2_w + (size_t)l * EH * DD,
            e2_b + (size_t)l * DD,
            e2f + (size_t)l * 4096,
            c1f + (size_t)l * 4096,
            gate_w + (size_t)l * DD,
            gate_b + l,
            c1_b + (size_t)l * 128,
            c2_w + (size_t)l * 128,
            c2_b + l,
            n1_w + (size_t)l * 64 * 64,
            n1_b + (size_t)l * 64,
            n2_w + (size_t)l * 64 * 32,
            n2_b + (size_t)l * DD,
            cscale + l,
            fouts[l], couts[l]);
        fin = fouts[l];
        cin = couts[l];
    }
}

// Round 10
// 328.831 us; speedup vs baseline: 2.5491x; 1.1017x over previous
//
#include <hip/hip_runtime.h>
#include <hip/hip_bf16.h>
#include <math.h>

#define BB 4
#define NN 1024
#define KK 128
#define DD 32
#define LL 3
#define EH 130
#define EHP 132

typedef float f32x4 __attribute__((ext_vector_type(4)));
typedef short s16x8 __attribute__((ext_vector_type(8)));

__device__ __forceinline__ float lrelu(float x) { return fmaxf(x, 0.1f * x); }

__device__ __forceinline__ unsigned pk2(float a, float b) {   // v_cvt_pk_bf16_f32 (RNE)
    __hip_bfloat162 h = __float22bfloat162_rn(float2{a, b});
    return *(unsigned*)&h;
}
__device__ __forceinline__ unsigned short bf16_hu(float v) {
    return (unsigned short)((__float_as_uint(v) + 0x8000u) >> 16);
}
__device__ __forceinline__ unsigned short bf16_rne(float v) {
    unsigned u = __float_as_uint(v);
    return (unsigned short)((u + 0x7fffu + ((u >> 16) & 1u)) >> 16);
}

// ---------------- fused: embed (blocks 0..511) + B-fragment precompute (512..607) ----------------
__global__ __launch_bounds__(256) void prep_kernel(
    const float* __restrict__ feat, const float* __restrict__ ew, const float* __restrict__ eb,
    float* __restrict__ out,
    const float* __restrict__ e2w, const float* __restrict__ c1w,
    unsigned short* __restrict__ e2f, unsigned short* __restrict__ c1f) {
    if (blockIdx.x < 512) {
        int t = blockIdx.x * 256 + threadIdx.x;
        if (t >= BB * NN * DD) return;
        int n = t >> 5, o = t & 31;
        const float* f = feat + n * DD;
        float a = eb[o];
#pragma unroll
        for (int k = 0; k < DD; k++) a = fmaf(f[k], ew[k * DD + o], a);
        out[t] = lrelu(a);
    } else {
        int t = (blockIdx.x - 512) * 256 + threadIdx.x;
        if (t < LL * 4 * 2 * 512) {
            int jj = t & 7, lane = (t >> 3) & 63, nt = (t >> 9) & 1, c = (t >> 10) & 3, l = t >> 12;
            int k = 32 * c + (lane >> 4) * 8 + jj;
            int n = nt * 16 + (lane & 15);
            e2f[t] = bf16_rne(e2w[(size_t)l * EH * DD + k * DD + n]);
        } else {
            int u = t - LL * 4 * 2 * 512;
            if (u < LL * 8 * 512) {
                int jj = u & 7, lane = (u >> 3) & 63, nt = (u >> 9) & 7, l = u >> 12;
                int k = (lane >> 4) * 8 + jj;
                int n = nt * 16 + (lane & 15);
                c1f[u] = bf16_rne(c1w[(size_t)l * DD * 128 + k * 128 + n]);
            }
        }
    }
}

// ---------------- fused: wave-per-node KNN (blocks 0..1023) + HI/HJ precompute ----------------
// KNN: exact top-K set matching jax.lax.top_k(-dist,K) incl. lower-index tie-break.
// One wave per node; 16 keys/lane in VGPRs. dstar via 31-step MSB-first binary
// search; wave counts use __ballot+__popcll (v_cmp -> SGPR mask + scalar popcount,
// NO ds_bpermute chains — the R9 latency bug). Gather likewise ballot-based.
__global__ __launch_bounds__(256) void knnpre_kernel(
    const float* __restrict__ coors, int* __restrict__ nbr,
    const float* __restrict__ feats, const float* __restrict__ e1w, const float* __restrict__ e1b,
    float* __restrict__ HI, float* __restrict__ HJ) {
    const int KNNB = BB * NN / 4;      // 1024 blocks, 4 waves each
    if (blockIdx.x >= KNNB) {
        // ---- pre part
        int t = (int)(blockIdx.x - KNNB) * 256 + threadIdx.x;
        if (t >= BB * NN * EHP) return;
        int n = t / EHP, o = t % EHP;
        if (o >= EH) { HI[t] = 0.f; HJ[t] = 0.f; return; }
        const float* f = feats + n * DD;
        float a = e1b[o], c = 0.f;
#pragma unroll
        for (int k = 0; k < DD; k++) a = fmaf(f[k], e1w[k * EH + o], a);
#pragma unroll
        for (int k = 0; k < DD; k++) c = fmaf(f[k], e1w[(DD + k) * EH + o], c);
        HI[t] = a;
        HJ[t] = c;
        return;
    }
    // ---- knn part: node = 4*blockIdx + waveId
    const int node = (int)blockIdx.x * 4 + (threadIdx.x >> 6);
    const int b = node >> 10, i = node & (NN - 1);
    const int lane = threadIdx.x & 63;

    const float2* cb = (const float2*)(coors + (size_t)b * NN * 2);
    const float2 ci = cb[i];
    unsigned k[16];
#pragma unroll
    for (int s = 0; s < 16; s++) {
        float2 cj = cb[lane + 64 * s];
        float dx = ci.x - cj.x, dy = ci.y - cj.y;
        // match numpy per-op rounding exactly (no fma contraction)
        float d = __fadd_rn(__fmul_rn(dx, dx), __fmul_rn(dy, dy));
        k[s] = __float_as_uint(d);
    }

    // dstar = 128th smallest (sorted[127]): MSB-first bitwise construction.
    // count(keys < P|2^bpos) < K  =>  that bit of sorted[K-1] is 1.
    unsigned P = 0;
    for (int bpos = 30; bpos >= 0; bpos--) {
        const unsigned X = P | (1u << bpos);
        unsigned c = 0;
#pragma unroll
        for (int s = 0; s < 16; s++)
            c += (unsigned)__popcll(__ballot(k[s] < X));
        if (c < (unsigned)KK) P = X;
    }
    const unsigned dstar = P;

    // gather keys < dstar via per-s ballot (slot = run + popc(mask & below))
    const unsigned long long below = (1ull << lane) - 1ull;
    int* nb = nbr + (size_t)node * KK;
    unsigned run = 0;
#pragma unroll
    for (int s = 0; s < 16; s++) {
        unsigned long long m = __ballot(k[s] < dstar);
        if (k[s] < dstar) nb[run + (unsigned)__popcll(m & below)] = lane + 64 * s;
        run += (unsigned)__popcll(m);
    }

    // ties (== dstar) in ascending index order until K filled
    const int need = KK - (int)run;    // >= 1
    unsigned tie = 0;
    for (int s = 0; s < 16 && (int)tie < need; s++) {
        unsigned long long m = __ballot(k[s] == dstar);
        if (k[s] == dstar) {
            unsigned r = tie + (unsigned)__popcll(m & below);
            if ((int)r < need) nb[run + r] = lane + 64 * s;
        }
        tie += (unsigned)__popcll(m);
    }
}

// ---------------- fused layer: MFMA e2 + gate + MFMA c1 + reductions + node MLP ----------------
// Round-10 change: software-pipelined HJ gather (chunk c+1 prefetched into registers
// while chunk c computes) — the 8 L2-hit dwordx4 loads were on the critical path.
__global__ __launch_bounds__(128) void layer_kernel(
    const float* __restrict__ feats_in, const float* __restrict__ coors_in,
    const int*   __restrict__ nbr,
    const float* __restrict__ HI, const float* __restrict__ HJ,
    const float* __restrict__ w65,
    const float* __restrict__ e2w,
    const float* __restrict__ e2b,
    const unsigned short* __restrict__ e2f,
    const unsigned short* __restrict__ c1f,
    const float* __restrict__ gw, const float* __restrict__ gb,
    const float* __restrict__ c1b, const float* __restrict__ c2w, const float* __restrict__ c2b,
    const float* __restrict__ n1w, const float* __restrict__ n1b,
    const float* __restrict__ n2w, const float* __restrict__ n2b,
    const float* __restrict__ scale,
    float* __restrict__ feats_out, float* __restrict__ coors_out) {
    const int node = blockIdx.x;
    const int b = node >> 10;
    const int t = threadIdx.x;
    const int lane = t & 63, wid = t >> 6;
    const int ln = lane & 15, q = lane >> 4;
    const int rowbase = wid * 64;

    __shared__ __align__(16) float shi[EHP];
    __shared__ __align__(16) float sw65[EHP];
    __shared__ __align__(16) unsigned short smA[2 * 64 * 32];
    __shared__ float sx0[128], sx1[128], su[128], sv[128];
    __shared__ float sgw[DD], se2b[DD], sfi[DD];
    __shared__ float sc1b[128], sc2w[128];
    __shared__ float redm[2][DD], redc[2][2];
    __shared__ float sni[2 * DD], shd[2 * DD];

    for (int u = t; u < EHP; u += 128) {
        shi[u] = HI[(size_t)node * EHP + u];
        sw65[u] = (u < EH) ? w65[u] : 0.f;
    }
    if (t < DD) { sfi[t] = feats_in[node * DD + t]; sgw[t] = gw[t]; se2b[t] = e2b[t]; }
    sc1b[t] = c1b[t];
    sc2w[t] = c2w[t];
    __syncthreads();

    const float cix = coors_in[node * 2], ciy = coors_in[node * 2 + 1];
    const int j = nbr[(size_t)node * KK + t];
    const float2 cj = *(const float2*)(coors_in + ((size_t)(b * NN) + j) * 2);
    const float dx = cix - cj.x, dy = ciy - cj.y;
    const float rd = __fadd_rn(__fmul_rn(dx, dx), __fmul_rn(dy, dy));
    const float nrm = fmaxf(sqrtf(rd), 1e-8f);
    const float s = scale[0] / nrm;
    su[t] = dx * s;
    sv[t] = dy * s;

    {
        const float2 hjt = *(const float2*)(HJ + ((size_t)(b * NN) + j) * EHP + 128);
        sx0[t] = lrelu(shi[128] + hjt.x + rd * sw65[128]);
        sx1[t] = lrelu(shi[129] + hjt.y + rd * sw65[129]);
    }

    const float* hjb[4];
    float rdR[4];
#pragma unroll
    for (int mt = 0; mt < 4; mt++) {
        int jR = __shfl(j, mt * 16 + ln, 64);
        rdR[mt] = __shfl(rd, mt * 16 + ln, 64);
        hjb[mt] = HJ + ((size_t)(b * NN) + jR) * EHP;
    }

    const float4* shi4 = (const float4*)shi;
    const float4* sw4  = (const float4*)sw65;

    const f32x4 zz = {0.f, 0.f, 0.f, 0.f};
    f32x4 accA[4][2];
#pragma unroll
    for (int mt = 0; mt < 4; mt++) { accA[mt][0] = zz; accA[mt][1] = zz; }

    // prefetch chunk 0's HJ fragments
    float4 ha[4], hbv[4];
#pragma unroll
    for (int mt = 0; mt < 4; mt++) {
        const float4* hjp = (const float4*)(hjb[mt] + q * 8);
        ha[mt] = hjp[0];
        hbv[mt] = hjp[1];
    }

#pragma unroll 1
    for (int c = 0; c < 4; c++) {
        s16x8 b0 = *(const s16x8*)(e2f + ((c * 2 + 0) * 64 + lane) * 8);
        s16x8 b1 = *(const s16x8*)(e2f + ((c * 2 + 1) * 64 + lane) * 8);
        float4 nha[4], nhb[4];
        if (c < 3) {
#pragma unroll
            for (int mt = 0; mt < 4; mt++) {
                const float4* hjp = (const float4*)(hjb[mt] + (c + 1) * 32 + q * 8);
                nha[mt] = hjp[0];
                nhb[mt] = hjp[1];
            }
        }
        const int kb = c * 8 + q * 2;
        const float4 hi0 = shi4[kb], hi1 = shi4[kb + 1];
        const float4 wv0 = sw4[kb],  wv1 = sw4[kb + 1];
#pragma unroll
        for (int mt = 0; mt < 4; mt++) {
            const float r = rdR[mt];
            union { s16x8 v; unsigned u[4]; } A;
            A.u[0] = pk2(lrelu(hi0.x + ha[mt].x + r * wv0.x), lrelu(hi0.y + ha[mt].y + r * wv0.y));
            A.u[1] = pk2(lrelu(hi0.z + ha[mt].z + r * wv0.z), lrelu(hi0.w + ha[mt].w + r * wv0.w));
            A.u[2] = pk2(lrelu(hi1.x + hbv[mt].x + r * wv1.x), lrelu(hi1.y + hbv[mt].y + r * wv1.y));
            A.u[3] = pk2(lrelu(hi1.z + hbv[mt].z + r * wv1.z), lrelu(hi1.w + hbv[mt].w + r * wv1.w));
            accA[mt][0] = __builtin_amdgcn_mfma_f32_16x16x32_bf16(A.v, b0, accA[mt][0], 0, 0, 0);
            accA[mt][1] = __builtin_amdgcn_mfma_f32_16x16x32_bf16(A.v, b1, accA[mt][1], 0, 0, 0);
        }
#pragma unroll
        for (int mt = 0; mt < 4; mt++) { ha[mt] = nha[mt]; hbv[mt] = nhb[mt]; }
    }

#pragma unroll
    for (int nt = 0; nt < 2; nt++) {
        const int col = nt * 16 + ln;
        const float w128 = e2w[128 * DD + col];
        const float w129 = e2w[129 * DD + col];
        const float bv = se2b[col];
#pragma unroll
        for (int mt = 0; mt < 4; mt++)
#pragma unroll
            for (int r = 0; r < 4; r++) {
                const int row = rowbase + mt * 16 + q * 4 + r;
                accA[mt][nt][r] = lrelu(accA[mt][nt][r] + bv + sx0[row] * w128 + sx1[row] * w129);
            }
    }

    const float gbv = gb[0];
#pragma unroll
    for (int mt = 0; mt < 4; mt++) {
        float p[4];
#pragma unroll
        for (int r = 0; r < 4; r++)
            p[r] = accA[mt][0][r] * sgw[ln] + accA[mt][1][r] * sgw[16 + ln];
#pragma unroll
        for (int off = 1; off <= 8; off <<= 1)
#pragma unroll
            for (int r = 0; r < 4; r++) p[r] += __shfl_xor(p[r], off);
#pragma unroll
        for (int r = 0; r < 4; r++) {
            const float g = 1.f / (1.f + __expf(-(p[r] + gbv)));
            accA[mt][0][r] *= g;
            accA[mt][1][r] *= g;
        }
    }

    float mi0 = 0.f, mi1 = 0.f;
#pragma unroll
    for (int mt = 0; mt < 4; mt++)
#pragma unroll
        for (int r = 0; r < 4; r++) { mi0 += accA[mt][0][r]; mi1 += accA[mt][1][r]; }
    mi0 += __shfl_xor(mi0, 16); mi0 += __shfl_xor(mi0, 32);
    mi1 += __shfl_xor(mi1, 16); mi1 += __shfl_xor(mi1, 32);
    if (lane < 16) { redm[wid][lane] = mi0; redm[wid][16 + lane] = mi1; }

    unsigned short* smw = smA + wid * (64 * 32);
#pragma unroll
    for (int mt = 0; mt < 4; mt++)
#pragma unroll
        for (int nt = 0; nt < 2; nt++)
#pragma unroll
            for (int r = 0; r < 4; r++) {
                const int prow = (r << 4) | (4 * mt + q);
                smw[prow * 32 + nt * 16 + ln] = bf16_hu(accA[mt][nt][r]);
            }

    s16x8 a4[4];
#pragma unroll
    for (int mt = 0; mt < 4; mt++) {
        const int prow = ((ln & 3) << 4) | (4 * mt + (ln >> 2));
        a4[mt] = *(const s16x8*)(smw + prow * 32 + q * 8);
    }

    float cacc[4][4];
#pragma unroll
    for (int mt = 0; mt < 4; mt++)
#pragma unroll
        for (int r = 0; r < 4; r++) cacc[mt][r] = 0.f;

#pragma unroll 1
    for (int g = 0; g < 4; g++) {
        s16x8 bc0 = *(const s16x8*)(c1f + ((2 * g + 0) * 64 + lane) * 8);
        s16x8 bc1 = *(const s16x8*)(c1f + ((2 * g + 1) * 64 + lane) * 8);
        f32x4 c20[4], c21[4];
#pragma unroll
        for (int mt = 0; mt < 4; mt++) {
            c20[mt] = __builtin_amdgcn_mfma_f32_16x16x32_bf16(a4[mt], bc0, zz, 0, 0, 0);
            c21[mt] = __builtin_amdgcn_mfma_f32_16x16x32_bf16(a4[mt], bc1, zz, 0, 0, 0);
        }
#pragma unroll
        for (int h = 0; h < 2; h++) {
            const int col = (2 * g + h) * 16 + ln;
            const float c1bv = sc1b[col], c2wv = sc2w[col];
#pragma unroll
            for (int mt = 0; mt < 4; mt++)
#pragma unroll
                for (int r = 0; r < 4; r++) {
                    const float v = (h ? c21[mt][r] : c20[mt][r]) + c1bv;
                    cacc[mt][r] = fmaf(lrelu(v), c2wv, cacc[mt][r]);
                }
        }
    }
#pragma unroll
    for (int off = 1; off <= 8; off <<= 1)
#pragma unroll
        for (int mt = 0; mt < 4; mt++)
#pragma unroll
            for (int r = 0; r < 4; r++) cacc[mt][r] += __shfl_xor(cacc[mt][r], off);

    const float c2bv = c2b[0];
    float vxp = 0.f, vyp = 0.f;
    if (ln == 0) {
#pragma unroll
        for (int mt = 0; mt < 4; mt++)
#pragma unroll
            for (int r = 0; r < 4; r++) {
                const int row = rowbase + mt * 16 + q * 4 + r;
                const float cw = cacc[mt][r] + c2bv;
                vxp = fmaf(cw, su[row], vxp);
                vyp = fmaf(cw, sv[row], vyp);
            }
    }
    vxp += __shfl_xor(vxp, 16); vxp += __shfl_xor(vxp, 32);
    vyp += __shfl_xor(vyp, 16); vyp += __shfl_xor(vyp, 32);
    if (lane == 0) { redc[wid][0] = vxp; redc[wid][1] = vyp; }

    __syncthreads();
    if (t < DD) {
        sni[t] = sfi[t];
        sni[DD + t] = redm[0][t] + redm[1][t];
    }
    __syncthreads();
    if (t < 2 * DD) {
        float a = n1b[t];
#pragma unroll
        for (int k = 0; k < 2 * DD; k++) a = fmaf(sni[k], n1w[k * 2 * DD + t], a);
        shd[t] = lrelu(a);
    }
    __syncthreads();
    if (t < DD) {
        float a = n2b[t];
#pragma unroll
        for (int o = 0; o < 2 * DD; o++) a = fmaf(shd[o], n2w[o * DD + t], a);
        feats_out[node * DD + t] = a + sfi[t];
    }
    if (t == 0) {
        coors_out[node * 2] = cix + redc[0][0] + redc[1][0];
        coors_out[node * 2 + 1] = ciy + redc[0][1] + redc[1][1];
    }
}

extern "C" void kernel_launch(void* const* d_in, const int* in_sizes, int n_in,
                              void* d_out, int out_size, void* d_ws, size_t ws_size,
                              hipStream_t stream) {
    const float* feat_   = (const float*)d_in[0];
    const float* coor_   = (const float*)d_in[1];
    // d_in[2] = batch (int32, unused: equal-size graphs)
    const float* embed_w = (const float*)d_in[3];
    const float* embed_b = (const float*)d_in[4];
    const float* e1_w    = (const float*)d_in[5];
    const float* e1_b    = (const float*)d_in[6];
    const float* e2_w    = (const float*)d_in[7];
    const float* e2_b    = (const float*)d_in[8];
    const float* gate_w  = (const float*)d_in[9];
    const float* gate_b  = (const float*)d_in[10];
    const float* c1_w    = (const float*)d_in[11];
    const float* c1_b    = (const float*)d_in[12];
    const float* c2_w    = (const float*)d_in[13];
    const float* c2_b    = (const float*)d_in[14];
    const float* n1_w    = (const float*)d_in[15];
    const float* n1_b    = (const float*)d_in[16];
    const float* n2_w    = (const float*)d_in[17];
    const float* n2_b    = (const float*)d_in[18];
    const float* cscale  = (const float*)d_in[19];

    float* ws = (float*)d_ws;
    float* feats_a = ws;               ws += BB * NN * DD;
    float* feats_b = ws;               ws += BB * NN * DD;
    float* coors_a = ws;               ws += BB * NN * 2;
    float* coors_b = ws;               ws += BB * NN * 2;
    float* HI      = ws;               ws += BB * NN * EHP;
    float* HJ      = ws;               ws += BB * NN * EHP;
    unsigned short* e2f = (unsigned short*)ws;   // LL*4096 ushorts
    unsigned short* c1f = e2f + LL * 4096;       // LL*4096 ushorts
    ws += (2 * LL * 4096) / 2;
    int* nbr = (int*)ws;

    prep_kernel<<<512 + 96, 256, 0, stream>>>(feat_, embed_w, embed_b, feats_a,
                                              e2_w, c1_w, e2f, c1f);

    const int KNNB = BB * NN / 4;                   // 1024
    const int PREB = (BB * NN * EHP + 255) / 256;   // 2112
    const float* fin = feats_a;
    const float* cin = coor_;
    float* fouts[LL] = {feats_b, feats_a, (float*)d_out};
    float* couts[LL] = {coors_a, coors_b, coors_a};

    for (int l = 0; l < LL; l++) {
        knnpre_kernel<<<KNNB + PREB, 256, 0, stream>>>(
            cin, nbr, fin, e1_w + (size_t)l * 65 * EH, e1_b + (size_t)l * EH, HI, HJ);
        layer_kernel<<<BB * NN, 128, 0, stream>>>(
            fin, cin, nbr, HI, HJ,
            e1_w + ((size_t)l * 65 + 64) * EH,
            e2_w + (size_t)l * EH * DD,
            e2_b + (size_t)l * DD,
            e2f + (size_t)l * 4096,
            c1f + (size_t)l * 4096,
            gate_w + (size_t)l * DD,
            gate_b + l,
            c1_b + (size_t)l * 128,
            c2_w + (size_t)l * 128,
            c2_b + l,
            n1_w + (size_t)l * 64 * 64,
            n1_b + (size_t)l * 64,
            n2_w + (size_t)l * 64 * 32,
            n2_b + (size_t)l * DD,
            cscale + l,
            fouts[l], couts[l]);
        fin = fouts[l];
        cin = couts[l];
    }
}